// Round 4
// baseline (10691.996 us; speedup 1.0000x reference)
//
#include <hip/hip_runtime.h>
#include <hip/hip_bf16.h>

#define N_NODES 50000
#define DIM     256
#define NEXP    4
#define NLAYER  3
#define NEDGE   1600000
#define BN_EPS  1e-5f

// ---------------------------------------------------------------- utilities
static __device__ __forceinline__ float wave_reduce(float v) {
    #pragma unroll
    for (int off = 32; off; off >>= 1) v += __shfl_xor(v, off, 64);
    return v;
}

// ---------------------------------------------------------------- degrees
__global__ void k_deg(const int* __restrict__ src, const int* __restrict__ dst,
                      int* __restrict__ cnt_out, int* __restrict__ cnt_in) {
    int i = blockIdx.x * 256 + threadIdx.x;
    if (i < NEDGE) {
        atomicAdd(&cnt_out[src[i]], 1);
        atomicAdd(&cnt_in[dst[i]], 1);
    }
}

__global__ void k_norm(const int* __restrict__ cnt_out, const int* __restrict__ cnt_in,
                       float* __restrict__ nsrc, float* __restrict__ ndst) {
    int i = blockIdx.x * 256 + threadIdx.x;
    if (i < N_NODES) {
        nsrc[i] = rsqrtf(fmaxf((float)cnt_out[i], 1.f));
        ndst[i] = rsqrtf(fmaxf((float)cnt_in[i], 1.f));
    }
}

// exclusive scan of cnt_in -> offs (N+1), also copy to cursor
__global__ __launch_bounds__(1024) void k_scan(const int* __restrict__ cnt_in,
                                               int* __restrict__ offs,
                                               int* __restrict__ cursor) {
    __shared__ int ps[1024];
    const int CH = 49;                       // 1024*49 = 50176 >= 50000
    int t = threadIdx.x;
    int base = t * CH;
    int s = 0;
    for (int k = 0; k < CH; k++) { int i = base + k; if (i < N_NODES) s += cnt_in[i]; }
    ps[t] = s; __syncthreads();
    for (int off = 1; off < 1024; off <<= 1) {
        int v = ps[t];
        int u = (t >= off) ? ps[t - off] : 0;
        __syncthreads();
        ps[t] = v + u;
        __syncthreads();
    }
    int run = (t == 0) ? 0 : ps[t - 1];
    for (int k = 0; k < CH; k++) {
        int i = base + k;
        if (i < N_NODES) { offs[i] = run; cursor[i] = run; run += cnt_in[i]; }
    }
    if (t == 1023) offs[N_NODES] = ps[1023];
}

__global__ void k_fill(const int* __restrict__ src, const int* __restrict__ dst,
                       const float* __restrict__ nsrc,
                       int* __restrict__ cursor,
                       int* __restrict__ csr_s, float* __restrict__ csr_w) {
    int i = blockIdx.x * 256 + threadIdx.x;
    if (i < NEDGE) {
        int s = src[i], d = dst[i];
        int pos = atomicAdd(&cursor[d], 1);
        csr_s[pos] = s;
        csr_w[pos] = nsrc[s];
    }
}

// ---------------------------------------------------------------- embedding
__global__ void k_emb(const int* __restrict__ x, const float4* __restrict__ emb4,
                      float4* __restrict__ h4) {
    int i = blockIdx.x * 256 + threadIdx.x;   // N*64 float4s
    if (i < N_NODES * 64) {
        int n = i >> 6, c = i & 63;
        h4[i] = emb4[x[n] * 64 + c];
    }
}

// ---------------------------------------------------------------- gating: pid + (ga,gb) per node
// pair ids: (0,1)=0 (0,2)=1 (0,3)=2 (1,2)=3 (1,3)=4 (2,3)=5; ga = gate of lower-index expert
__global__ void k_gate(const float4* __restrict__ h4, const float4* __restrict__ wg4,
                       int* __restrict__ pid, float* __restrict__ gaN,
                       float* __restrict__ gbN) {
    int n    = blockIdx.x * 4 + (threadIdx.x >> 6);
    int lane = threadIdx.x & 63;
    if (n >= N_NODES) return;
    float4 hv = h4[n * 64 + lane];
    const float* hp = (const float*)&hv;
    float4 acc = {0.f, 0.f, 0.f, 0.f};
    #pragma unroll
    for (int j = 0; j < 4; j++) {
        float4 w = wg4[lane * 4 + j];   // w_gate[l][d][0..3]
        acc.x += hp[j] * w.x; acc.y += hp[j] * w.y;
        acc.z += hp[j] * w.z; acc.w += hp[j] * w.w;
    }
    acc.x = wave_reduce(acc.x); acc.y = wave_reduce(acc.y);
    acc.z = wave_reduce(acc.z); acc.w = wave_reduce(acc.w);
    if (lane == 0) {
        float lg[4] = {acc.x, acc.y, acc.z, acc.w};
        int e1 = 0;
        #pragma unroll
        for (int e = 1; e < 4; e++) if (lg[e] > lg[e1]) e1 = e;   // ties -> lower idx (top_k)
        int e2 = -1;
        #pragma unroll
        for (int e = 0; e < 4; e++) {
            if (e == e1) continue;
            if (e2 < 0 || lg[e] > lg[e2]) e2 = e;
        }
        float v1 = lg[e1], v2 = lg[e2];
        float g2 = 1.f / (1.f + expf(v1 - v2));   // softmax over {v1,v2}
        float g1 = 1.f - g2;
        int a = min(e1, e2), b = max(e1, e2);
        float ga = (e1 < e2) ? g1 : g2;
        float gb = (e1 < e2) ? g2 : g1;
        int p = (a == 0) ? (b - 1) : ((a == 1) ? (b + 1) : (b + 2));
        pid[n] = p; gaN[n] = ga; gbN[n] = gb;
    }
}

// ---------------------------------------------------------------- bucket nodes by pair id
__global__ void k_bucket(const int* __restrict__ pid, const float* __restrict__ gaN,
                         const float* __restrict__ gbN,
                         int* __restrict__ gcount, int* __restrict__ bnode,
                         float* __restrict__ bga, float* __restrict__ bgb) {
    __shared__ int cnt[6];
    __shared__ int basep[6];
    int t = threadIdx.x;
    int n = blockIdx.x * 256 + t;
    if (t < 6) cnt[t] = 0;
    __syncthreads();
    int p = 0, pos = 0;
    bool valid = (n < N_NODES);
    if (valid) { p = pid[n]; pos = atomicAdd(&cnt[p], 1); }
    __syncthreads();
    if (t < 6) basep[t] = atomicAdd(&gcount[t], cnt[t]);
    __syncthreads();
    if (valid) {
        int idx = basep[p] + pos;
        bnode[p * N_NODES + idx] = n;
        bga[p * N_NODES + idx]   = gaN[n];
        bgb[p * N_NODES + idx]   = gbN[n];
    }
}

// ---------------------------------------------------------------- aggregation (one wave / dst)
__global__ void k_agg(const float4* __restrict__ h4,
                      const int* __restrict__ offs,
                      const int* __restrict__ csr_s, const float* __restrict__ csr_w,
                      const float* __restrict__ ndst,
                      float4* __restrict__ agg4) {
    int n    = blockIdx.x * 4 + (threadIdx.x >> 6);
    int lane = threadIdx.x & 63;
    if (n >= N_NODES) return;
    int beg = offs[n], end = offs[n + 1];
    float4 acc = {0.f, 0.f, 0.f, 0.f};
    int j = beg;
    for (; j + 1 < end; j += 2) {          // unroll-2: two independent gathers in flight
        int   s0 = csr_s[j],     s1 = csr_s[j + 1];
        float w0 = csr_w[j],     w1 = csr_w[j + 1];
        float4 a = h4[(size_t)s0 * 64 + lane];
        float4 b = h4[(size_t)s1 * 64 + lane];
        acc.x += w0 * a.x + w1 * b.x; acc.y += w0 * a.y + w1 * b.y;
        acc.z += w0 * a.z + w1 * b.z; acc.w += w0 * a.w + w1 * b.w;
    }
    if (j < end) {
        int   s0 = csr_s[j];
        float w0 = csr_w[j];
        float4 a = h4[(size_t)s0 * 64 + lane];
        acc.x += w0 * a.x; acc.y += w0 * a.y; acc.z += w0 * a.z; acc.w += w0 * a.w;
    }
    float nd = ndst[n];
    acc.x *= nd; acc.y *= nd; acc.z *= nd; acc.w *= nd;
    agg4[n * 64 + lane] = acc;
}

// ---------------------------------------------------------------- column sums of agg
__global__ void k_colsum(const float* __restrict__ agg, float* __restrict__ msum) {
    int t = threadIdx.x;                       // 256 threads == 256 columns
    const int CH = 200;                        // 250*200 = 50000
    int n0 = blockIdx.x * CH;
    float s = 0.f;
    for (int r = 0; r < CH; r++) {
        int n = n0 + r;
        if (n < N_NODES) s += agg[n * DIM + t];
    }
    atomicAdd(&msum[t], s);
}

// ---------------------------------------------------------------- Gram partials (symmetric: 10 pairs)
#define GSL   64     // k-slices
#define GCH   784    // rows per slice: 64*784 = 50176 >= 50000
#define NPAIR 10
__global__ __launch_bounds__(256) void k_gram(const float* __restrict__ agg,
                                              float* __restrict__ Cp) {
    __shared__ float LA[16][64];
    __shared__ float LB[16][64];
    const int tiT[NPAIR] = {0,0,0,0,1,1,1,2,2,3};
    const int tjT[NPAIR] = {0,1,2,3,1,2,3,2,3,3};
    int t  = threadIdx.x;
    int sl = blockIdx.x;            // k-slice
    int pr = blockIdx.y;            // tile pair 0..9 (ti<=tj)
    int ti = tiT[pr], tj = tjT[pr];
    int tx = t & 15, ty = t >> 4;
    float acc[4][4] = {};
    int nbase = sl * GCH;
    const float4* agg4 = (const float4*)agg;
    for (int s0 = 0; s0 < GCH; s0 += 16) {
        int r = ty;                  // 16 rows staged, one per thread group
        int n = nbase + s0 + r;
        float4 va = {0.f, 0.f, 0.f, 0.f}, vb = {0.f, 0.f, 0.f, 0.f};
        if (n < N_NODES) {
            va = agg4[n * 64 + ti * 16 + tx];
            vb = agg4[n * 64 + tj * 16 + tx];
        }
        __syncthreads();
        *(float4*)&LA[r][tx * 4] = va;
        *(float4*)&LB[r][tx * 4] = vb;
        __syncthreads();
        #pragma unroll
        for (int rr = 0; rr < 16; rr++) {
            float4 a = *(const float4*)&LA[rr][tx * 4];
            float4 b = *(const float4*)&LB[rr][ty * 4];
            const float* af = (const float*)&a;
            const float* bf = (const float*)&b;
            #pragma unroll
            for (int i = 0; i < 4; i++)
                #pragma unroll
                for (int j = 0; j < 4; j++)
                    acc[i][j] += af[i] * bf[j];
        }
    }
    float* Cb = Cp + ((size_t)(sl * NPAIR + pr)) * 4096;
    #pragma unroll
    for (int i = 0; i < 4; i++) {
        float4 v; v.x = acc[i][0]; v.y = acc[i][1]; v.z = acc[i][2]; v.w = acc[i][3];
        *(float4*)&Cb[(tx * 4 + i) * 64 + ty * 4] = v;
    }
}

__global__ void k_gred(const float* __restrict__ Cp, float* __restrict__ Cm) {
    int gid = blockIdx.x * 256 + threadIdx.x;    // 65536
    int i = gid >> 8, j = gid & 255;
    int a = i >> 6, b = j >> 6, ii = i & 63, jj = j & 63;
    int ro = ii, co = jj;
    if (a > b) { int tmp = a; a = b; b = tmp; ro = jj; co = ii; }   // symmetric reconstruct
    int pr = (a == 0) ? b : ((a == 1) ? 3 + b : ((a == 2) ? 5 + b : 6 + b));
    const float* p = Cp + (size_t)pr * 4096 + ro * 64 + co;
    float s = 0.f;
    #pragma unroll 8
    for (int sl = 0; sl < GSL; sl++) s += p[(size_t)sl * NPAIR * 4096];
    Cm[gid] = s;
}

// ---------------------------------------------------------------- BN stats -> scale/shift
__global__ __launch_bounds__(256) void k_stats(const float* __restrict__ C,
                                               const float* __restrict__ msum,
                                               const float* __restrict__ conv_W,
                                               const float* __restrict__ bn_gamma,
                                               const float* __restrict__ bn_beta,
                                               float* __restrict__ scaleb,
                                               float* __restrict__ shiftb, int l) {
    int e = blockIdx.x >> 8, f = blockIdx.x & 255;
    int t = threadIdx.x;
    __shared__ float wsh[256];
    __shared__ float red[256];
    const float* W = conv_W + (size_t)(l * NEXP + e) * DIM * DIM;  // [d][f]
    wsh[t] = W[t * DIM + f];
    __syncthreads();
    float v = 0.f;
    #pragma unroll 8
    for (int d2 = 0; d2 < DIM; d2++) v += C[d2 * DIM + t] * wsh[d2];  // C symmetric: column read
    float a_t = msum[t] * (1.f / (float)N_NODES);
    float qp  = wsh[t] * v;
    float ap  = a_t * wsh[t];
    red[t] = qp; __syncthreads();
    for (int off = 128; off; off >>= 1) { if (t < off) red[t] += red[t + off]; __syncthreads(); }
    float q = red[0];                       // only t==0 uses it
    red[t] = ap; __syncthreads();
    for (int off = 128; off; off >>= 1) { if (t < off) red[t] += red[t + off]; __syncthreads(); }
    if (t == 0) {
        float aw  = red[0];
        float var = q * (1.f / (float)N_NODES) - aw * aw;
        var = fmaxf(var, 0.f);
        float sg = bn_gamma[(l * NEXP + e) * DIM + f] * rsqrtf(var + BN_EPS);
        scaleb[e * DIM + f] = sg;
        shiftb[e * DIM + f] = bn_beta[(l * NEXP + e) * DIM + f] - aw * sg;
    }
}

__global__ void k_wscale(const float* __restrict__ conv_W, const float* __restrict__ scaleb,
                         float* __restrict__ Ws, int l) {
    int i = blockIdx.x * 256 + threadIdx.x;     // NEXP*DIM*DIM
    if (i < NEXP * DIM * DIM) {
        int e = i >> 16, f = i & 255;
        Ws[i] = conv_W[(size_t)l * NEXP * DIM * DIM + i] * scaleb[e * DIM + f];
    }
}

// ---------------------------------------------------------------- pair-bucketed MoE GEMM, K=512
// h_out[n,f] = v + relu(v), v = ga*(agg·Ws[ea])_f + gb*(agg·Ws[eb])_f + ga*sh[ea][f] + gb*sh[eb][f]
__global__ __launch_bounds__(256, 3) void k_moe(const float4* __restrict__ agg4,
                                                const float* __restrict__ Ws,
                                                const float* __restrict__ shiftb,
                                                const int* __restrict__ gcount,
                                                const int* __restrict__ bnode,
                                                const float* __restrict__ bga,
                                                const float* __restrict__ bgb,
                                                float* __restrict__ hout) {
    __shared__ float As[2][16][68];     // transposed A' slab, pad 68 (bank-conflict-free, b128-aligned)
    __shared__ float WB[2][16][256];
    __shared__ int   nds[64];
    __shared__ float gA[64], gB[64];
    __shared__ float shc[2][256];
    int p    = blockIdx.y;
    int cnt  = gcount[p];
    int base = blockIdx.x * 64;
    if (base >= cnt) return;
    const int eaT[6] = {0,0,0,1,1,2};
    const int ebT[6] = {1,2,3,2,3,3};
    int ea = eaT[p], eb = ebT[p];
    int t  = threadIdx.x;
    if (t < 64) {
        int idx = base + t;
        if (idx < cnt) {
            nds[t] = bnode[p * N_NODES + idx];
            gA[t]  = bga[p * N_NODES + idx];
            gB[t]  = bgb[p * N_NODES + idx];
        } else { nds[t] = -1; gA[t] = 0.f; gB[t] = 0.f; }
    }
    if (t < 128) {   // stage both shift rows (2*256 floats = 128 float4)
        int which = t >> 6, c = t & 63;
        int e = which ? eb : ea;
        ((float4*)shc[which])[c] = ((const float4*)(shiftb + e * DIM))[c];
    }
    __syncthreads();

    int rA = t >> 2, cA = t & 3;       // staging role: row rA, k-chunk cA
    int rg = t >> 4, cg = t & 15;
    int r0 = rg * 4, c4 = cg * 4;

    float4 av, w0, w1, w2, w3;
    auto LOADG = [&](int s) {
        int esel = s >> 4;             // 0: expert ea (k<256), 1: expert eb
        int n = nds[rA];
        av = make_float4(0.f, 0.f, 0.f, 0.f);
        if (n >= 0) {
            // NOTE: (s & 15) — both experts consume the SAME agg row columns;
            // round-3 bug read s*4 (overflow into next node's row) for s>=16.
            av = agg4[(size_t)n * 64 + ((s & 15) * 4 + cA)];
            float g = esel ? gB[rA] : gA[rA];
            av.x *= g; av.y *= g; av.z *= g; av.w *= g;
        }
        const float4* W4 = (const float4*)(Ws + ((esel ? eb : ea) << 16) + ((s & 15) << 12));
        w0 = W4[t]; w1 = W4[t + 256]; w2 = W4[t + 512]; w3 = W4[t + 768];
    };
    auto STORELDS = [&](int b) {
        As[b][cA * 4 + 0][rA] = av.x;
        As[b][cA * 4 + 1][rA] = av.y;
        As[b][cA * 4 + 2][rA] = av.z;
        As[b][cA * 4 + 3][rA] = av.w;
        float4* WB4 = (float4*)WB[b];
        WB4[t] = w0; WB4[t + 256] = w1; WB4[t + 512] = w2; WB4[t + 768] = w3;
    };

    float acc[4][16] = {};
    LOADG(0);
    STORELDS(0);
    __syncthreads();
    for (int s = 0; s < 32; s++) {
        int cur = s & 1;
        if (s < 31) LOADG(s + 1);
        #pragma unroll
        for (int dd = 0; dd < 16; dd++) {
            float4 a = *(const float4*)&As[cur][dd][r0];     // b128, rows r0..r0+3
            const float* af = (const float*)&a;
            #pragma unroll
            for (int q = 0; q < 4; q++) {
                float4 w = *(const float4*)&WB[cur][dd][q * 64 + c4];
                const float* wf = (const float*)&w;
                #pragma unroll
                for (int i = 0; i < 4; i++)
                    #pragma unroll
                    for (int k = 0; k < 4; k++)
                        acc[i][q * 4 + k] += af[i] * wf[k];
            }
        }
        if (s < 31) STORELDS(cur ^ 1);
        __syncthreads();
    }

    // epilogue
    #pragma unroll
    for (int i = 0; i < 4; i++) {
        int row = r0 + i;
        int n = nds[row];
        if (n < 0) continue;
        float ga = gA[row], gb = gB[row];
        #pragma unroll
        for (int q = 0; q < 4; q++) {
            int col = q * 64 + c4;
            float4 o;
            float* of = (float*)&o;
            #pragma unroll
            for (int k = 0; k < 4; k++) {
                float v = acc[i][q * 4 + k] + ga * shc[0][col + k] + gb * shc[1][col + k];
                of[k] = v + fmaxf(v, 0.f);
            }
            *(float4*)(hout + (size_t)n * DIM + col) = o;
        }
    }
}

// ================================================================ host
extern "C" void kernel_launch(void* const* d_in, const int* in_sizes, int n_in,
                              void* d_out, int out_size, void* d_ws, size_t ws_size,
                              hipStream_t stream) {
    const int*   x        = (const int*)d_in[0];
    const int*   ei       = (const int*)d_in[1];
    const float* emb      = (const float*)d_in[2];
    const float* w_gate   = (const float*)d_in[3];
    const float* conv_W   = (const float*)d_in[4];
    // conv_b (d_in[5]) cancels exactly in the BN fold — unused
    const float* bn_gamma = (const float*)d_in[6];
    const float* bn_beta  = (const float*)d_in[7];
    float* out = (float*)d_out;

    const int* src = ei;
    const int* dst = ei + NEDGE;

    char* ws = (char*)d_ws;
    size_t off = 0;
    auto alloc = [&](size_t bytes) -> void* {
        void* p = ws + off;
        off += (bytes + 255) & ~(size_t)255;
        return p;
    };
    float* h        = (float*)alloc((size_t)N_NODES * DIM * 4);   // single h buffer (in-place layers)
    float* agg      = (float*)alloc((size_t)N_NODES * DIM * 4);
    int*   cnt_out  = (int*)  alloc((size_t)N_NODES * 4);
    int*   cnt_in   = (int*)  alloc((size_t)N_NODES * 4);
    float* nsrc     = (float*)alloc((size_t)N_NODES * 4);
    float* ndst     = (float*)alloc((size_t)N_NODES * 4);
    int*   offs     = (int*)  alloc((size_t)(N_NODES + 1) * 4);
    int*   cursor   = (int*)  alloc((size_t)N_NODES * 4);
    int*   csr_s    = (int*)  alloc((size_t)NEDGE * 4);
    float* csr_w    = (float*)alloc((size_t)NEDGE * 4);
    int*   pid      = (int*)  alloc((size_t)N_NODES * 4);
    float* gaN      = (float*)alloc((size_t)N_NODES * 4);
    float* gbN      = (float*)alloc((size_t)N_NODES * 4);
    int*   gcount   = (int*)  alloc(6 * 4);
    int*   bnode    = (int*)  alloc((size_t)6 * N_NODES * 4);
    float* bga      = (float*)alloc((size_t)6 * N_NODES * 4);
    float* bgb      = (float*)alloc((size_t)6 * N_NODES * 4);
    float* Cp       = (float*)alloc((size_t)GSL * NPAIR * 4096 * 4); // 10.5 MB gram partials
    float* Cm       = (float*)alloc((size_t)DIM * DIM * 4);
    float* msum     = (float*)alloc((size_t)DIM * 4);
    float* scaleb   = (float*)alloc((size_t)NEXP * DIM * 4);
    float* shiftb   = (float*)alloc((size_t)NEXP * DIM * 4);
    float* Wsbuf    = (float*)alloc((size_t)NEXP * DIM * DIM * 4);
    (void)ws_size; (void)in_sizes; (void)n_in; (void)out_size;

    // ---- graph structure (per call; inputs are restored every call)
    hipMemsetAsync(cnt_out, 0, (size_t)N_NODES * 4, stream);
    hipMemsetAsync(cnt_in,  0, (size_t)N_NODES * 4, stream);
    k_deg <<<(NEDGE + 255) / 256, 256, 0, stream>>>(src, dst, cnt_out, cnt_in);
    k_norm<<<(N_NODES + 255) / 256, 256, 0, stream>>>(cnt_out, cnt_in, nsrc, ndst);
    k_scan<<<1, 1024, 0, stream>>>(cnt_in, offs, cursor);
    k_fill<<<(NEDGE + 255) / 256, 256, 0, stream>>>(src, dst, nsrc, cursor, csr_s, csr_w);
    k_emb <<<(N_NODES * 64 + 255) / 256, 256, 0, stream>>>(x, (const float4*)emb, (float4*)h);

    for (int l = 0; l < NLAYER; l++) {
        float* hout = (l == NLAYER - 1) ? out : h;   // k_moe reads only agg+buckets: in-place OK

        k_gate<<<N_NODES / 4, 256, 0, stream>>>((const float4*)h,
                (const float4*)(w_gate + (size_t)l * DIM * NEXP), pid, gaN, gbN);
        hipMemsetAsync(gcount, 0, 6 * 4, stream);
        k_bucket<<<(N_NODES + 255) / 256, 256, 0, stream>>>(pid, gaN, gbN,
                gcount, bnode, bga, bgb);
        k_agg<<<N_NODES / 4, 256, 0, stream>>>((const float4*)h, offs, csr_s, csr_w,
                ndst, (float4*)agg);

        hipMemsetAsync(msum, 0, (size_t)DIM * 4, stream);
        k_colsum<<<250, 256, 0, stream>>>(agg, msum);
        k_gram<<<dim3(GSL, NPAIR), 256, 0, stream>>>(agg, Cp);
        k_gred<<<DIM * DIM / 256, 256, 0, stream>>>(Cp, Cm);
        k_stats<<<NEXP * DIM, 256, 0, stream>>>(Cm, msum, conv_W, bn_gamma, bn_beta,
                                                scaleb, shiftb, l);
        k_wscale<<<(NEXP * DIM * DIM + 255) / 256, 256, 0, stream>>>(conv_W, scaleb, Wsbuf, l);

        k_moe<<<dim3((N_NODES + 63) / 64, 6), 256, 0, stream>>>((const float4*)agg,
                Wsbuf, shiftb, gcount, bnode, bga, bgb, hout);
    }
}

// Round 5
// 2630.851 us; speedup vs baseline: 4.0641x; 4.0641x over previous
//
#include <hip/hip_runtime.h>
#include <hip/hip_bf16.h>

#define N_NODES 50000
#define DIM     256
#define NEXP    4
#define NLAYER  3
#define NEDGE   1600000
#define BN_EPS  1e-5f

// ---------------------------------------------------------------- utilities
static __device__ __forceinline__ float wave_reduce(float v) {
    #pragma unroll
    for (int off = 32; off; off >>= 1) v += __shfl_xor(v, off, 64);
    return v;
}

// ---------------------------------------------------------------- degrees
__global__ void k_deg(const int* __restrict__ src, const int* __restrict__ dst,
                      int* __restrict__ cnt_out, int* __restrict__ cnt_in) {
    int i = blockIdx.x * 256 + threadIdx.x;
    if (i < NEDGE) {
        atomicAdd(&cnt_out[src[i]], 1);
        atomicAdd(&cnt_in[dst[i]], 1);
    }
}

__global__ void k_norm(const int* __restrict__ cnt_out, const int* __restrict__ cnt_in,
                       float* __restrict__ nsrc, float* __restrict__ ndst) {
    int i = blockIdx.x * 256 + threadIdx.x;
    if (i < N_NODES) {
        nsrc[i] = rsqrtf(fmaxf((float)cnt_out[i], 1.f));
        ndst[i] = rsqrtf(fmaxf((float)cnt_in[i], 1.f));
    }
}

// exclusive scan of cnt_in -> offs (N+1), also copy to cursor
__global__ __launch_bounds__(1024) void k_scan(const int* __restrict__ cnt_in,
                                               int* __restrict__ offs,
                                               int* __restrict__ cursor) {
    __shared__ int ps[1024];
    const int CH = 49;                       // 1024*49 = 50176 >= 50000
    int t = threadIdx.x;
    int base = t * CH;
    int s = 0;
    for (int k = 0; k < CH; k++) { int i = base + k; if (i < N_NODES) s += cnt_in[i]; }
    ps[t] = s; __syncthreads();
    for (int off = 1; off < 1024; off <<= 1) {
        int v = ps[t];
        int u = (t >= off) ? ps[t - off] : 0;
        __syncthreads();
        ps[t] = v + u;
        __syncthreads();
    }
    int run = (t == 0) ? 0 : ps[t - 1];
    for (int k = 0; k < CH; k++) {
        int i = base + k;
        if (i < N_NODES) { offs[i] = run; cursor[i] = run; run += cnt_in[i]; }
    }
    if (t == 1023) offs[N_NODES] = ps[1023];
}

__global__ void k_fill(const int* __restrict__ src, const int* __restrict__ dst,
                       const float* __restrict__ nsrc,
                       int* __restrict__ cursor,
                       int* __restrict__ csr_s, float* __restrict__ csr_w) {
    int i = blockIdx.x * 256 + threadIdx.x;
    if (i < NEDGE) {
        int s = src[i], d = dst[i];
        int pos = atomicAdd(&cursor[d], 1);
        csr_s[pos] = s;
        csr_w[pos] = nsrc[s];
    }
}

// ---------------------------------------------------------------- embedding
__global__ void k_emb(const int* __restrict__ x, const float4* __restrict__ emb4,
                      float4* __restrict__ h4) {
    int i = blockIdx.x * 256 + threadIdx.x;   // N*64 float4s
    if (i < N_NODES * 64) {
        int n = i >> 6, c = i & 63;
        h4[i] = emb4[x[n] * 64 + c];
    }
}

// ---------------------------------------------------------------- gating: pid + (ga,gb) per node
// pair ids: (0,1)=0 (0,2)=1 (0,3)=2 (1,2)=3 (1,3)=4 (2,3)=5; ga = gate of lower-index expert
__global__ void k_gate(const float4* __restrict__ h4, const float4* __restrict__ wg4,
                       int* __restrict__ pid, float* __restrict__ gaN,
                       float* __restrict__ gbN) {
    int n    = blockIdx.x * 4 + (threadIdx.x >> 6);
    int lane = threadIdx.x & 63;
    if (n >= N_NODES) return;
    float4 hv = h4[n * 64 + lane];
    const float* hp = (const float*)&hv;
    float4 acc = {0.f, 0.f, 0.f, 0.f};
    #pragma unroll
    for (int j = 0; j < 4; j++) {
        float4 w = wg4[lane * 4 + j];   // w_gate[l][d][0..3]
        acc.x += hp[j] * w.x; acc.y += hp[j] * w.y;
        acc.z += hp[j] * w.z; acc.w += hp[j] * w.w;
    }
    acc.x = wave_reduce(acc.x); acc.y = wave_reduce(acc.y);
    acc.z = wave_reduce(acc.z); acc.w = wave_reduce(acc.w);
    if (lane == 0) {
        float lg[4] = {acc.x, acc.y, acc.z, acc.w};
        int e1 = 0;
        #pragma unroll
        for (int e = 1; e < 4; e++) if (lg[e] > lg[e1]) e1 = e;   // ties -> lower idx (top_k)
        int e2 = -1;
        #pragma unroll
        for (int e = 0; e < 4; e++) {
            if (e == e1) continue;
            if (e2 < 0 || lg[e] > lg[e2]) e2 = e;
        }
        float v1 = lg[e1], v2 = lg[e2];
        float g2 = 1.f / (1.f + expf(v1 - v2));   // softmax over {v1,v2}
        float g1 = 1.f - g2;
        int a = min(e1, e2), b = max(e1, e2);
        float ga = (e1 < e2) ? g1 : g2;
        float gb = (e1 < e2) ? g2 : g1;
        int p = (a == 0) ? (b - 1) : ((a == 1) ? (b + 1) : (b + 2));
        pid[n] = p; gaN[n] = ga; gbN[n] = gb;
    }
}

// ---------------------------------------------------------------- bucket nodes by pair id
__global__ void k_bucket(const int* __restrict__ pid, const float* __restrict__ gaN,
                         const float* __restrict__ gbN,
                         int* __restrict__ gcount, int* __restrict__ bnode,
                         float* __restrict__ bga, float* __restrict__ bgb) {
    __shared__ int cnt[6];
    __shared__ int basep[6];
    int t = threadIdx.x;
    int n = blockIdx.x * 256 + t;
    if (t < 6) cnt[t] = 0;
    __syncthreads();
    int p = 0, pos = 0;
    bool valid = (n < N_NODES);
    if (valid) { p = pid[n]; pos = atomicAdd(&cnt[p], 1); }
    __syncthreads();
    if (t < 6) basep[t] = atomicAdd(&gcount[t], cnt[t]);
    __syncthreads();
    if (valid) {
        int idx = basep[p] + pos;
        bnode[p * N_NODES + idx] = n;
        bga[p * N_NODES + idx]   = gaN[n];
        bgb[p * N_NODES + idx]   = gbN[n];
    }
}

// ---------------------------------------------------------------- aggregation (one wave / dst)
__global__ void k_agg(const float4* __restrict__ h4,
                      const int* __restrict__ offs,
                      const int* __restrict__ csr_s, const float* __restrict__ csr_w,
                      const float* __restrict__ ndst,
                      float4* __restrict__ agg4) {
    int n    = blockIdx.x * 4 + (threadIdx.x >> 6);
    int lane = threadIdx.x & 63;
    if (n >= N_NODES) return;
    int beg = offs[n], end = offs[n + 1];
    float4 acc = {0.f, 0.f, 0.f, 0.f};
    int j = beg;
    for (; j + 1 < end; j += 2) {          // unroll-2: two independent gathers in flight
        int   s0 = csr_s[j],     s1 = csr_s[j + 1];
        float w0 = csr_w[j],     w1 = csr_w[j + 1];
        float4 a = h4[(size_t)s0 * 64 + lane];
        float4 b = h4[(size_t)s1 * 64 + lane];
        acc.x += w0 * a.x + w1 * b.x; acc.y += w0 * a.y + w1 * b.y;
        acc.z += w0 * a.z + w1 * b.z; acc.w += w0 * a.w + w1 * b.w;
    }
    if (j < end) {
        int   s0 = csr_s[j];
        float w0 = csr_w[j];
        float4 a = h4[(size_t)s0 * 64 + lane];
        acc.x += w0 * a.x; acc.y += w0 * a.y; acc.z += w0 * a.z; acc.w += w0 * a.w;
    }
    float nd = ndst[n];
    acc.x *= nd; acc.y *= nd; acc.z *= nd; acc.w *= nd;
    agg4[n * 64 + lane] = acc;
}

// ---------------------------------------------------------------- column sums of agg
__global__ void k_colsum(const float* __restrict__ agg, float* __restrict__ msum) {
    int t = threadIdx.x;                       // 256 threads == 256 columns
    const int CH = 200;                        // 250*200 = 50000
    int n0 = blockIdx.x * CH;
    float s = 0.f;
    for (int r = 0; r < CH; r++) {
        int n = n0 + r;
        if (n < N_NODES) s += agg[n * DIM + t];
    }
    atomicAdd(&msum[t], s);
}

// ---------------------------------------------------------------- Gram partials (symmetric: 10 pairs)
#define GSL   64     // k-slices
#define GCH   784    // rows per slice: 64*784 = 50176 >= 50000
#define NPAIR 10
__global__ __launch_bounds__(256) void k_gram(const float* __restrict__ agg,
                                              float* __restrict__ Cp) {
    __shared__ float LA[16][64];
    __shared__ float LB[16][64];
    const int tiT[NPAIR] = {0,0,0,0,1,1,1,2,2,3};
    const int tjT[NPAIR] = {0,1,2,3,1,2,3,2,3,3};
    int t  = threadIdx.x;
    int sl = blockIdx.x;            // k-slice
    int pr = blockIdx.y;            // tile pair 0..9 (ti<=tj)
    int ti = tiT[pr], tj = tjT[pr];
    int tx = t & 15, ty = t >> 4;
    float acc[4][4] = {};
    int nbase = sl * GCH;
    const float4* agg4 = (const float4*)agg;
    for (int s0 = 0; s0 < GCH; s0 += 16) {
        int r = ty;                  // 16 rows staged, one per thread group
        int n = nbase + s0 + r;
        float4 va = {0.f, 0.f, 0.f, 0.f}, vb = {0.f, 0.f, 0.f, 0.f};
        if (n < N_NODES) {
            va = agg4[n * 64 + ti * 16 + tx];
            vb = agg4[n * 64 + tj * 16 + tx];
        }
        __syncthreads();
        *(float4*)&LA[r][tx * 4] = va;
        *(float4*)&LB[r][tx * 4] = vb;
        __syncthreads();
        #pragma unroll
        for (int rr = 0; rr < 16; rr++) {
            float4 a = *(const float4*)&LA[rr][tx * 4];
            float4 b = *(const float4*)&LB[rr][ty * 4];
            const float* af = (const float*)&a;
            const float* bf = (const float*)&b;
            #pragma unroll
            for (int i = 0; i < 4; i++)
                #pragma unroll
                for (int j = 0; j < 4; j++)
                    acc[i][j] += af[i] * bf[j];
        }
    }
    float* Cb = Cp + ((size_t)(sl * NPAIR + pr)) * 4096;
    #pragma unroll
    for (int i = 0; i < 4; i++) {
        float4 v; v.x = acc[i][0]; v.y = acc[i][1]; v.z = acc[i][2]; v.w = acc[i][3];
        *(float4*)&Cb[(tx * 4 + i) * 64 + ty * 4] = v;
    }
}

__global__ void k_gred(const float* __restrict__ Cp, float* __restrict__ Cm) {
    int gid = blockIdx.x * 256 + threadIdx.x;    // 65536
    int i = gid >> 8, j = gid & 255;
    int a = i >> 6, b = j >> 6, ii = i & 63, jj = j & 63;
    int ro = ii, co = jj;
    if (a > b) { int tmp = a; a = b; b = tmp; ro = jj; co = ii; }   // symmetric reconstruct
    int pr = (a == 0) ? b : ((a == 1) ? 3 + b : ((a == 2) ? 5 + b : 6 + b));
    const float* p = Cp + (size_t)pr * 4096 + ro * 64 + co;
    float s = 0.f;
    #pragma unroll 8
    for (int sl = 0; sl < GSL; sl++) s += p[(size_t)sl * NPAIR * 4096];
    Cm[gid] = s;
}

// ---------------------------------------------------------------- BN stats -> scale/shift
__global__ __launch_bounds__(256) void k_stats(const float* __restrict__ C,
                                               const float* __restrict__ msum,
                                               const float* __restrict__ conv_W,
                                               const float* __restrict__ bn_gamma,
                                               const float* __restrict__ bn_beta,
                                               float* __restrict__ scaleb,
                                               float* __restrict__ shiftb, int l) {
    int e = blockIdx.x >> 8, f = blockIdx.x & 255;
    int t = threadIdx.x;
    __shared__ float wsh[256];
    __shared__ float red[256];
    const float* W = conv_W + (size_t)(l * NEXP + e) * DIM * DIM;  // [d][f]
    wsh[t] = W[t * DIM + f];
    __syncthreads();
    float v = 0.f;
    #pragma unroll 8
    for (int d2 = 0; d2 < DIM; d2++) v += C[d2 * DIM + t] * wsh[d2];  // C symmetric: column read
    float a_t = msum[t] * (1.f / (float)N_NODES);
    float qp  = wsh[t] * v;
    float ap  = a_t * wsh[t];
    red[t] = qp; __syncthreads();
    for (int off = 128; off; off >>= 1) { if (t < off) red[t] += red[t + off]; __syncthreads(); }
    float q = red[0];                       // only t==0 uses it
    red[t] = ap; __syncthreads();
    for (int off = 128; off; off >>= 1) { if (t < off) red[t] += red[t + off]; __syncthreads(); }
    if (t == 0) {
        float aw  = red[0];
        float var = q * (1.f / (float)N_NODES) - aw * aw;
        var = fmaxf(var, 0.f);
        float sg = bn_gamma[(l * NEXP + e) * DIM + f] * rsqrtf(var + BN_EPS);
        scaleb[e * DIM + f] = sg;
        shiftb[e * DIM + f] = bn_beta[(l * NEXP + e) * DIM + f] - aw * sg;
    }
}

__global__ void k_wscale(const float* __restrict__ conv_W, const float* __restrict__ scaleb,
                         float* __restrict__ Ws, int l) {
    int i = blockIdx.x * 256 + threadIdx.x;     // NEXP*DIM*DIM
    if (i < NEXP * DIM * DIM) {
        int e = i >> 16, f = i & 255;
        Ws[i] = conv_W[(size_t)l * NEXP * DIM * DIM + i] * scaleb[e * DIM + f];
    }
}

// ---------------------------------------------------------------- pair-bucketed MoE GEMM, K=512
// h_out[n,f] = v + relu(v), v = ga*(agg·Ws[ea])_f + gb*(agg·Ws[eb])_f + ga*sh[ea][f] + gb*sh[eb][f]
// NOTE: no lambdas — round-4's [&]-capturing LOADG/STORELDS forced the staging
// registers (av, w0..w3) into scratch: 6.9 GB WRITE_SIZE, VALUBusy 3%, 7.6x slowdown.
__global__ __launch_bounds__(256) void k_moe(const float4* __restrict__ agg4,
                                             const float* __restrict__ Ws,
                                             const float* __restrict__ shiftb,
                                             const int* __restrict__ gcount,
                                             const int* __restrict__ bnode,
                                             const float* __restrict__ bga,
                                             const float* __restrict__ bgb,
                                             float* __restrict__ hout) {
    __shared__ float As[2][16][68];     // transposed A' slab, pad 68 (2-way max -> free)
    __shared__ float WB[2][16][256];
    __shared__ int   nds[64];
    __shared__ float gA[64], gB[64];
    __shared__ float shc[2][256];
    int p    = blockIdx.y;
    int cnt  = gcount[p];
    int base = blockIdx.x * 64;
    if (base >= cnt) return;
    const int eaT[6] = {0,0,0,1,1,2};
    const int ebT[6] = {1,2,3,2,3,3};
    int ea = eaT[p], eb = ebT[p];
    int t  = threadIdx.x;
    if (t < 64) {
        int idx = base + t;
        if (idx < cnt) {
            nds[t] = bnode[p * N_NODES + idx];
            gA[t]  = bga[p * N_NODES + idx];
            gB[t]  = bgb[p * N_NODES + idx];
        } else { nds[t] = -1; gA[t] = 0.f; gB[t] = 0.f; }
    }
    if (t < 128) {   // stage both shift rows (2*256 floats = 128 float4)
        int which = t >> 6, c = t & 63;
        int e = which ? eb : ea;
        ((float4*)shc[which])[c] = ((const float4*)(shiftb + e * DIM))[c];
    }
    __syncthreads();

    int rA = t >> 2, cA = t & 3;       // staging role: row rA, k-chunk cA
    int rg = t >> 4, cg = t & 15;
    int r0 = rg * 4, c4 = cg * 4;

    // register-cache per-thread staging metadata (constant across stages)
    int   nrow = nds[rA];
    float gar  = gA[rA], gbr = gB[rA];
    const float4* aggrow = agg4 + (size_t)(nrow < 0 ? 0 : nrow) * 64;

    // ---- stage 0 load + store (buf 0)
    float4 av = make_float4(0.f, 0.f, 0.f, 0.f);
    if (nrow >= 0) {
        av = aggrow[cA];               // stage 0: k-chunk cA
        av.x *= gar; av.y *= gar; av.z *= gar; av.w *= gar;
    }
    {
        const float4* W4 = (const float4*)(Ws + (ea << 16));
        float4 w0 = W4[t], w1 = W4[t + 256], w2 = W4[t + 512], w3 = W4[t + 768];
        As[0][cA * 4 + 0][rA] = av.x;
        As[0][cA * 4 + 1][rA] = av.y;
        As[0][cA * 4 + 2][rA] = av.z;
        As[0][cA * 4 + 3][rA] = av.w;
        float4* WB4 = (float4*)WB[0];
        WB4[t] = w0; WB4[t + 256] = w1; WB4[t + 512] = w2; WB4[t + 768] = w3;
    }
    __syncthreads();

    float acc[4][16] = {};
    for (int s = 0; s < 32; s++) {
        int cur = s & 1;
        // ---- issue next stage's global loads (registers, inline)
        float4 nav = make_float4(0.f, 0.f, 0.f, 0.f);
        float4 nw0, nw1, nw2, nw3;
        if (s < 31) {
            int s1   = s + 1;
            int esel = s1 >> 4;
            int kk   = s1 & 15;
            if (nrow >= 0) {
                nav = aggrow[kk * 4 + cA];
                float g = esel ? gbr : gar;
                nav.x *= g; nav.y *= g; nav.z *= g; nav.w *= g;
            }
            const float4* W4 = (const float4*)(Ws + ((esel ? eb : ea) << 16) + (kk << 12));
            nw0 = W4[t]; nw1 = W4[t + 256]; nw2 = W4[t + 512]; nw3 = W4[t + 768];
        }
        // ---- compute current stage from LDS buf[cur]
        #pragma unroll
        for (int dd = 0; dd < 16; dd++) {
            float4 a = *(const float4*)&As[cur][dd][r0];     // rows r0..r0+3 at k=dd
            const float* af = (const float*)&a;
            #pragma unroll
            for (int q = 0; q < 4; q++) {
                float4 w = *(const float4*)&WB[cur][dd][q * 64 + c4];
                const float* wf = (const float*)&w;
                #pragma unroll
                for (int i = 0; i < 4; i++)
                    #pragma unroll
                    for (int k = 0; k < 4; k++)
                        acc[i][q * 4 + k] += af[i] * wf[k];
            }
        }
        // ---- store next stage into buf[cur^1]
        if (s < 31) {
            int nb = cur ^ 1;
            As[nb][cA * 4 + 0][rA] = nav.x;
            As[nb][cA * 4 + 1][rA] = nav.y;
            As[nb][cA * 4 + 2][rA] = nav.z;
            As[nb][cA * 4 + 3][rA] = nav.w;
            float4* WB4 = (float4*)WB[nb];
            WB4[t] = nw0; WB4[t + 256] = nw1; WB4[t + 512] = nw2; WB4[t + 768] = nw3;
        }
        __syncthreads();
    }

    // epilogue
    #pragma unroll
    for (int i = 0; i < 4; i++) {
        int row = r0 + i;
        int n = nds[row];
        if (n < 0) continue;
        float ga = gA[row], gb = gB[row];
        #pragma unroll
        for (int q = 0; q < 4; q++) {
            int col = q * 64 + c4;
            float4 o;
            float* of = (float*)&o;
            #pragma unroll
            for (int k = 0; k < 4; k++) {
                float v = acc[i][q * 4 + k] + ga * shc[0][col + k] + gb * shc[1][col + k];
                of[k] = v + fmaxf(v, 0.f);
            }
            *(float4*)(hout + (size_t)n * DIM + col) = o;
        }
    }
}

// ================================================================ host
extern "C" void kernel_launch(void* const* d_in, const int* in_sizes, int n_in,
                              void* d_out, int out_size, void* d_ws, size_t ws_size,
                              hipStream_t stream) {
    const int*   x        = (const int*)d_in[0];
    const int*   ei       = (const int*)d_in[1];
    const float* emb      = (const float*)d_in[2];
    const float* w_gate   = (const float*)d_in[3];
    const float* conv_W   = (const float*)d_in[4];
    // conv_b (d_in[5]) cancels exactly in the BN fold — unused
    const float* bn_gamma = (const float*)d_in[6];
    const float* bn_beta  = (const float*)d_in[7];
    float* out = (float*)d_out;

    const int* src = ei;
    const int* dst = ei + NEDGE;

    char* ws = (char*)d_ws;
    size_t off = 0;
    auto alloc = [&](size_t bytes) -> void* {
        void* p = ws + off;
        off += (bytes + 255) & ~(size_t)255;
        return p;
    };
    float* h        = (float*)alloc((size_t)N_NODES * DIM * 4);   // single h buffer (in-place layers)
    float* agg      = (float*)alloc((size_t)N_NODES * DIM * 4);
    int*   cnt_out  = (int*)  alloc((size_t)N_NODES * 4);
    int*   cnt_in   = (int*)  alloc((size_t)N_NODES * 4);
    float* nsrc     = (float*)alloc((size_t)N_NODES * 4);
    float* ndst     = (float*)alloc((size_t)N_NODES * 4);
    int*   offs     = (int*)  alloc((size_t)(N_NODES + 1) * 4);
    int*   cursor   = (int*)  alloc((size_t)N_NODES * 4);
    int*   csr_s    = (int*)  alloc((size_t)NEDGE * 4);
    float* csr_w    = (float*)alloc((size_t)NEDGE * 4);
    int*   pid      = (int*)  alloc((size_t)N_NODES * 4);
    float* gaN      = (float*)alloc((size_t)N_NODES * 4);
    float* gbN      = (float*)alloc((size_t)N_NODES * 4);
    int*   gcount   = (int*)  alloc(6 * 4);
    int*   bnode    = (int*)  alloc((size_t)6 * N_NODES * 4);
    float* bga      = (float*)alloc((size_t)6 * N_NODES * 4);
    float* bgb      = (float*)alloc((size_t)6 * N_NODES * 4);
    float* Cp       = (float*)alloc((size_t)GSL * NPAIR * 4096 * 4); // 10.5 MB gram partials
    float* Cm       = (float*)alloc((size_t)DIM * DIM * 4);
    float* msum     = (float*)alloc((size_t)DIM * 4);
    float* scaleb   = (float*)alloc((size_t)NEXP * DIM * 4);
    float* shiftb   = (float*)alloc((size_t)NEXP * DIM * 4);
    float* Wsbuf    = (float*)alloc((size_t)NEXP * DIM * DIM * 4);
    (void)ws_size; (void)in_sizes; (void)n_in; (void)out_size;

    // ---- graph structure (per call; inputs are restored every call)
    hipMemsetAsync(cnt_out, 0, (size_t)N_NODES * 4, stream);
    hipMemsetAsync(cnt_in,  0, (size_t)N_NODES * 4, stream);
    k_deg <<<(NEDGE + 255) / 256, 256, 0, stream>>>(src, dst, cnt_out, cnt_in);
    k_norm<<<(N_NODES + 255) / 256, 256, 0, stream>>>(cnt_out, cnt_in, nsrc, ndst);
    k_scan<<<1, 1024, 0, stream>>>(cnt_in, offs, cursor);
    k_fill<<<(NEDGE + 255) / 256, 256, 0, stream>>>(src, dst, nsrc, cursor, csr_s, csr_w);
    k_emb <<<(N_NODES * 64 + 255) / 256, 256, 0, stream>>>(x, (const float4*)emb, (float4*)h);

    for (int l = 0; l < NLAYER; l++) {
        float* hout = (l == NLAYER - 1) ? out : h;   // k_moe reads only agg+buckets: in-place OK

        k_gate<<<N_NODES / 4, 256, 0, stream>>>((const float4*)h,
                (const float4*)(w_gate + (size_t)l * DIM * NEXP), pid, gaN, gbN);
        hipMemsetAsync(gcount, 0, 6 * 4, stream);
        k_bucket<<<(N_NODES + 255) / 256, 256, 0, stream>>>(pid, gaN, gbN,
                gcount, bnode, bga, bgb);
        k_agg<<<N_NODES / 4, 256, 0, stream>>>((const float4*)h, offs, csr_s, csr_w,
                ndst, (float4*)agg);

        hipMemsetAsync(msum, 0, (size_t)DIM * 4, stream);
        k_colsum<<<250, 256, 0, stream>>>(agg, msum);
        k_gram<<<dim3(GSL, NPAIR), 256, 0, stream>>>(agg, Cp);
        k_gred<<<DIM * DIM / 256, 256, 0, stream>>>(Cp, Cm);
        k_stats<<<NEXP * DIM, 256, 0, stream>>>(Cm, msum, conv_W, bn_gamma, bn_beta,
                                                scaleb, shiftb, l);
        k_wscale<<<(NEXP * DIM * DIM + 255) / 256, 256, 0, stream>>>(conv_W, scaleb, Wsbuf, l);

        k_moe<<<dim3((N_NODES + 63) / 64, 6), 256, 0, stream>>>((const float4*)agg,
                Wsbuf, shiftb, gcount, bnode, bga, bgb, hout);
    }
}

// Round 6
// 2248.834 us; speedup vs baseline: 4.7545x; 1.1699x over previous
//
#include <hip/hip_runtime.h>
#include <hip/hip_bf16.h>

#define N_NODES 50000
#define DIM     256
#define NEXP    4
#define NLAYER  3
#define NEDGE   1600000
#define BN_EPS  1e-5f

// ---------------------------------------------------------------- utilities
static __device__ __forceinline__ float wave_reduce(float v) {
    #pragma unroll
    for (int off = 32; off; off >>= 1) v += __shfl_xor(v, off, 64);
    return v;
}

// ---------------------------------------------------------------- degrees
__global__ void k_deg(const int* __restrict__ src, const int* __restrict__ dst,
                      int* __restrict__ cnt_out, int* __restrict__ cnt_in) {
    int i = blockIdx.x * 256 + threadIdx.x;
    if (i < NEDGE) {
        atomicAdd(&cnt_out[src[i]], 1);
        atomicAdd(&cnt_in[dst[i]], 1);
    }
}

__global__ void k_norm(const int* __restrict__ cnt_out, const int* __restrict__ cnt_in,
                       float* __restrict__ nsrc, float* __restrict__ ndst) {
    int i = blockIdx.x * 256 + threadIdx.x;
    if (i < N_NODES) {
        nsrc[i] = rsqrtf(fmaxf((float)cnt_out[i], 1.f));
        ndst[i] = rsqrtf(fmaxf((float)cnt_in[i], 1.f));
    }
}

// exclusive scan of cnt_in -> offs (N+1), also copy to cursor
__global__ __launch_bounds__(1024) void k_scan(const int* __restrict__ cnt_in,
                                               int* __restrict__ offs,
                                               int* __restrict__ cursor) {
    __shared__ int ps[1024];
    const int CH = 49;                       // 1024*49 = 50176 >= 50000
    int t = threadIdx.x;
    int base = t * CH;
    int s = 0;
    for (int k = 0; k < CH; k++) { int i = base + k; if (i < N_NODES) s += cnt_in[i]; }
    ps[t] = s; __syncthreads();
    for (int off = 1; off < 1024; off <<= 1) {
        int v = ps[t];
        int u = (t >= off) ? ps[t - off] : 0;
        __syncthreads();
        ps[t] = v + u;
        __syncthreads();
    }
    int run = (t == 0) ? 0 : ps[t - 1];
    for (int k = 0; k < CH; k++) {
        int i = base + k;
        if (i < N_NODES) { offs[i] = run; cursor[i] = run; run += cnt_in[i]; }
    }
    if (t == 1023) offs[N_NODES] = ps[1023];
}

__global__ void k_fill(const int* __restrict__ src, const int* __restrict__ dst,
                       const float* __restrict__ nsrc,
                       int* __restrict__ cursor,
                       int* __restrict__ csr_s, float* __restrict__ csr_w) {
    int i = blockIdx.x * 256 + threadIdx.x;
    if (i < NEDGE) {
        int s = src[i], d = dst[i];
        int pos = atomicAdd(&cursor[d], 1);
        csr_s[pos] = s;
        csr_w[pos] = nsrc[s];
    }
}

// ---------------------------------------------------------------- embedding
__global__ void k_emb(const int* __restrict__ x, const float4* __restrict__ emb4,
                      float4* __restrict__ h4) {
    int i = blockIdx.x * 256 + threadIdx.x;   // N*64 float4s
    if (i < N_NODES * 64) {
        int n = i >> 6, c = i & 63;
        h4[i] = emb4[x[n] * 64 + c];
    }
}

// ---------------------------------------------------------------- gating: pid + (ga,gb) per node
// pair ids: (0,1)=0 (0,2)=1 (0,3)=2 (1,2)=3 (1,3)=4 (2,3)=5; ga = gate of lower-index expert
__global__ void k_gate(const float4* __restrict__ h4, const float4* __restrict__ wg4,
                       int* __restrict__ pid, float* __restrict__ gaN,
                       float* __restrict__ gbN) {
    int n    = blockIdx.x * 4 + (threadIdx.x >> 6);
    int lane = threadIdx.x & 63;
    if (n >= N_NODES) return;
    float4 hv = h4[n * 64 + lane];
    const float* hp = (const float*)&hv;
    float4 acc = {0.f, 0.f, 0.f, 0.f};
    #pragma unroll
    for (int j = 0; j < 4; j++) {
        float4 w = wg4[lane * 4 + j];   // w_gate[l][d][0..3]
        acc.x += hp[j] * w.x; acc.y += hp[j] * w.y;
        acc.z += hp[j] * w.z; acc.w += hp[j] * w.w;
    }
    acc.x = wave_reduce(acc.x); acc.y = wave_reduce(acc.y);
    acc.z = wave_reduce(acc.z); acc.w = wave_reduce(acc.w);
    if (lane == 0) {
        float lg[4] = {acc.x, acc.y, acc.z, acc.w};
        int e1 = 0;
        #pragma unroll
        for (int e = 1; e < 4; e++) if (lg[e] > lg[e1]) e1 = e;   // ties -> lower idx (top_k)
        int e2 = -1;
        #pragma unroll
        for (int e = 0; e < 4; e++) {
            if (e == e1) continue;
            if (e2 < 0 || lg[e] > lg[e2]) e2 = e;
        }
        float v1 = lg[e1], v2 = lg[e2];
        float g2 = 1.f / (1.f + expf(v1 - v2));   // softmax over {v1,v2}
        float g1 = 1.f - g2;
        int a = min(e1, e2), b = max(e1, e2);
        float ga = (e1 < e2) ? g1 : g2;
        float gb = (e1 < e2) ? g2 : g1;
        int p = (a == 0) ? (b - 1) : ((a == 1) ? (b + 1) : (b + 2));
        pid[n] = p; gaN[n] = ga; gbN[n] = gb;
    }
}

// ---------------------------------------------------------------- bucket nodes by pair id
__global__ void k_bucket(const int* __restrict__ pid, const float* __restrict__ gaN,
                         const float* __restrict__ gbN,
                         int* __restrict__ gcount, int* __restrict__ bnode,
                         float* __restrict__ bga, float* __restrict__ bgb) {
    __shared__ int cnt[6];
    __shared__ int basep[6];
    int t = threadIdx.x;
    int n = blockIdx.x * 256 + t;
    if (t < 6) cnt[t] = 0;
    __syncthreads();
    int p = 0, pos = 0;
    bool valid = (n < N_NODES);
    if (valid) { p = pid[n]; pos = atomicAdd(&cnt[p], 1); }
    __syncthreads();
    if (t < 6) basep[t] = atomicAdd(&gcount[t], cnt[t]);
    __syncthreads();
    if (valid) {
        int idx = basep[p] + pos;
        bnode[p * N_NODES + idx] = n;
        bga[p * N_NODES + idx]   = gaN[n];
        bgb[p * N_NODES + idx]   = gbN[n];
    }
}

// ---------------------------------------------------------------- aggregation (one wave / dst)
__global__ void k_agg(const float4* __restrict__ h4,
                      const int* __restrict__ offs,
                      const int* __restrict__ csr_s, const float* __restrict__ csr_w,
                      const float* __restrict__ ndst,
                      float4* __restrict__ agg4) {
    int n    = blockIdx.x * 4 + (threadIdx.x >> 6);
    int lane = threadIdx.x & 63;
    if (n >= N_NODES) return;
    int beg = offs[n], end = offs[n + 1];
    float4 acc = {0.f, 0.f, 0.f, 0.f};
    int j = beg;
    for (; j + 1 < end; j += 2) {          // unroll-2: two independent gathers in flight
        int   s0 = csr_s[j],     s1 = csr_s[j + 1];
        float w0 = csr_w[j],     w1 = csr_w[j + 1];
        float4 a = h4[(size_t)s0 * 64 + lane];
        float4 b = h4[(size_t)s1 * 64 + lane];
        acc.x += w0 * a.x + w1 * b.x; acc.y += w0 * a.y + w1 * b.y;
        acc.z += w0 * a.z + w1 * b.z; acc.w += w0 * a.w + w1 * b.w;
    }
    if (j < end) {
        int   s0 = csr_s[j];
        float w0 = csr_w[j];
        float4 a = h4[(size_t)s0 * 64 + lane];
        acc.x += w0 * a.x; acc.y += w0 * a.y; acc.z += w0 * a.z; acc.w += w0 * a.w;
    }
    float nd = ndst[n];
    acc.x *= nd; acc.y *= nd; acc.z *= nd; acc.w *= nd;
    agg4[n * 64 + lane] = acc;
}

// ---------------------------------------------------------------- column sums of agg
__global__ void k_colsum(const float* __restrict__ agg, float* __restrict__ msum) {
    int t = threadIdx.x;                       // 256 threads == 256 columns
    const int CH = 200;                        // 250*200 = 50000
    int n0 = blockIdx.x * CH;
    float s = 0.f;
    for (int r = 0; r < CH; r++) {
        int n = n0 + r;
        if (n < N_NODES) s += agg[n * DIM + t];
    }
    atomicAdd(&msum[t], s);
}

// ---------------------------------------------------------------- Gram partials (symmetric: 10 pairs)
#define GSL   64     // k-slices
#define GCH   784    // rows per slice: 64*784 = 50176 >= 50000
#define NPAIR 10
__global__ __launch_bounds__(256) void k_gram(const float* __restrict__ agg,
                                              float* __restrict__ Cp) {
    __shared__ float LA[16][64];
    __shared__ float LB[16][64];
    const int tiT[NPAIR] = {0,0,0,0,1,1,1,2,2,3};
    const int tjT[NPAIR] = {0,1,2,3,1,2,3,2,3,3};
    int t  = threadIdx.x;
    int sl = blockIdx.x;            // k-slice
    int pr = blockIdx.y;            // tile pair 0..9 (ti<=tj)
    int ti = tiT[pr], tj = tjT[pr];
    int tx = t & 15, ty = t >> 4;
    float acc[4][4] = {};
    int nbase = sl * GCH;
    const float4* agg4 = (const float4*)agg;
    for (int s0 = 0; s0 < GCH; s0 += 16) {
        int r = ty;                  // 16 rows staged, one per thread group
        int n = nbase + s0 + r;
        float4 va = {0.f, 0.f, 0.f, 0.f}, vb = {0.f, 0.f, 0.f, 0.f};
        if (n < N_NODES) {
            va = agg4[n * 64 + ti * 16 + tx];
            vb = agg4[n * 64 + tj * 16 + tx];
        }
        __syncthreads();
        *(float4*)&LA[r][tx * 4] = va;
        *(float4*)&LB[r][tx * 4] = vb;
        __syncthreads();
        #pragma unroll
        for (int rr = 0; rr < 16; rr++) {
            float4 a = *(const float4*)&LA[rr][tx * 4];
            float4 b = *(const float4*)&LB[rr][ty * 4];
            const float* af = (const float*)&a;
            const float* bf = (const float*)&b;
            #pragma unroll
            for (int i = 0; i < 4; i++)
                #pragma unroll
                for (int j = 0; j < 4; j++)
                    acc[i][j] += af[i] * bf[j];
        }
    }
    float* Cb = Cp + ((size_t)(sl * NPAIR + pr)) * 4096;
    #pragma unroll
    for (int i = 0; i < 4; i++) {
        float4 v; v.x = acc[i][0]; v.y = acc[i][1]; v.z = acc[i][2]; v.w = acc[i][3];
        *(float4*)&Cb[(tx * 4 + i) * 64 + ty * 4] = v;
    }
}

__global__ void k_gred(const float* __restrict__ Cp, float* __restrict__ Cm) {
    int gid = blockIdx.x * 256 + threadIdx.x;    // 65536
    int i = gid >> 8, j = gid & 255;
    int a = i >> 6, b = j >> 6, ii = i & 63, jj = j & 63;
    int ro = ii, co = jj;
    if (a > b) { int tmp = a; a = b; b = tmp; ro = jj; co = ii; }   // symmetric reconstruct
    int pr = (a == 0) ? b : ((a == 1) ? 3 + b : ((a == 2) ? 5 + b : 6 + b));
    const float* p = Cp + (size_t)pr * 4096 + ro * 64 + co;
    float s = 0.f;
    #pragma unroll 8
    for (int sl = 0; sl < GSL; sl++) s += p[(size_t)sl * NPAIR * 4096];
    Cm[gid] = s;
}

// ---------------------------------------------------------------- BN stats -> scale/shift
__global__ __launch_bounds__(256) void k_stats(const float* __restrict__ C,
                                               const float* __restrict__ msum,
                                               const float* __restrict__ conv_W,
                                               const float* __restrict__ bn_gamma,
                                               const float* __restrict__ bn_beta,
                                               float* __restrict__ scaleb,
                                               float* __restrict__ shiftb, int l) {
    int e = blockIdx.x >> 8, f = blockIdx.x & 255;
    int t = threadIdx.x;
    __shared__ float wsh[256];
    __shared__ float red[256];
    const float* W = conv_W + (size_t)(l * NEXP + e) * DIM * DIM;  // [d][f]
    wsh[t] = W[t * DIM + f];
    __syncthreads();
    float v = 0.f;
    #pragma unroll 8
    for (int d2 = 0; d2 < DIM; d2++) v += C[d2 * DIM + t] * wsh[d2];  // C symmetric: column read
    float a_t = msum[t] * (1.f / (float)N_NODES);
    float qp  = wsh[t] * v;
    float ap  = a_t * wsh[t];
    red[t] = qp; __syncthreads();
    for (int off = 128; off; off >>= 1) { if (t < off) red[t] += red[t + off]; __syncthreads(); }
    float q = red[0];                       // only t==0 uses it
    red[t] = ap; __syncthreads();
    for (int off = 128; off; off >>= 1) { if (t < off) red[t] += red[t + off]; __syncthreads(); }
    if (t == 0) {
        float aw  = red[0];
        float var = q * (1.f / (float)N_NODES) - aw * aw;
        var = fmaxf(var, 0.f);
        float sg = bn_gamma[(l * NEXP + e) * DIM + f] * rsqrtf(var + BN_EPS);
        scaleb[e * DIM + f] = sg;
        shiftb[e * DIM + f] = bn_beta[(l * NEXP + e) * DIM + f] - aw * sg;
    }
}

__global__ void k_wscale(const float* __restrict__ conv_W, const float* __restrict__ scaleb,
                         float* __restrict__ Ws, int l) {
    int i = blockIdx.x * 256 + threadIdx.x;     // NEXP*DIM*DIM
    if (i < NEXP * DIM * DIM) {
        int e = i >> 16, f = i & 255;
        Ws[i] = conv_W[(size_t)l * NEXP * DIM * DIM + i] * scaleb[e * DIM + f];
    }
}

// ---------------------------------------------------------------- pair-bucketed MoE GEMM, K=512
// h_out[n,f] = v + relu(v), v = ga*(agg·Ws[ea])_f + gb*(agg·Ws[eb])_f + ga*sh[ea][f] + gb*sh[eb][f]
// Structure notes (hard-won):
//  * No [&]-lambdas for staging (round 4: regs demoted to scratch, 6.9 GB spill traffic).
//  * Single-buffer LDS + 2 barriers/stage (round 2 structure: compiled to 64 VGPRs) —
//    round 5's explicit double-buffer ballooned to 216 VGPRs -> 8.9% occupancy.
//    Loads for stage s+1 issue right after the store of stage s -> in flight across compute.
//  * As transposed [k][row] with pad 68: A-read b128 2-way/broadcast (free),
//    W-read 2-way (free) per m136.
__global__ __launch_bounds__(256) void k_moe(const float4* __restrict__ agg4,
                                             const float* __restrict__ Ws,
                                             const float* __restrict__ shiftb,
                                             const int* __restrict__ gcount,
                                             const int* __restrict__ bnode,
                                             const float* __restrict__ bga,
                                             const float* __restrict__ bgb,
                                             float* __restrict__ hout) {
    __shared__ float As[16][68];      // 4.25 KB transposed A' slab
    __shared__ float WB[16][256];     // 16 KB
    __shared__ int   nds[64];
    __shared__ float gA[64], gB[64];
    __shared__ float shc[2][256];
    int p    = blockIdx.y;
    int cnt  = gcount[p];
    int base = blockIdx.x * 64;
    if (base >= cnt) return;
    const int eaT[6] = {0,0,0,1,1,2};
    const int ebT[6] = {1,2,3,2,3,3};
    int ea = eaT[p], eb = ebT[p];
    int t  = threadIdx.x;
    if (t < 64) {
        int idx = base + t;
        if (idx < cnt) {
            nds[t] = bnode[p * N_NODES + idx];
            gA[t]  = bga[p * N_NODES + idx];
            gB[t]  = bgb[p * N_NODES + idx];
        } else { nds[t] = -1; gA[t] = 0.f; gB[t] = 0.f; }
    }
    if (t < 128) {   // stage both shift rows (2*256 floats = 128 float4)
        int which = t >> 6, c = t & 63;
        int e = which ? eb : ea;
        ((float4*)shc[which])[c] = ((const float4*)(shiftb + e * DIM))[c];
    }
    __syncthreads();

    int rA = t >> 2, cA = t & 3;       // staging role: row rA, k-chunk cA
    int rg = t >> 4, cg = t & 15;
    int r0 = rg * 4, c4 = cg * 4;

    // register-cache per-thread staging metadata (constant across stages)
    int   nrow = nds[rA];
    float gar  = gA[rA], gbr = gB[rA];
    const float4* aggrow = agg4 + (size_t)(nrow < 0 ? 0 : nrow) * 64;

    // ---- stage-0 loads into regs
    float4 av = make_float4(0.f, 0.f, 0.f, 0.f);
    if (nrow >= 0) {
        av = aggrow[cA];
        av.x *= gar; av.y *= gar; av.z *= gar; av.w *= gar;
    }
    const float4* W4 = (const float4*)(Ws + (ea << 16));
    float4 w0 = W4[t], w1 = W4[t + 256], w2 = W4[t + 512], w3 = W4[t + 768];

    float acc[4][16] = {};
    for (int s = 0; s < 32; s++) {
        // ---- store staged regs into LDS (single buffer)
        __syncthreads();               // previous compute done reading LDS
        As[cA * 4 + 0][rA] = av.x;
        As[cA * 4 + 1][rA] = av.y;
        As[cA * 4 + 2][rA] = av.z;
        As[cA * 4 + 3][rA] = av.w;
        {
            float4* WB4 = (float4*)WB;
            WB4[t] = w0; WB4[t + 256] = w1; WB4[t + 512] = w2; WB4[t + 768] = w3;
        }
        __syncthreads();
        // ---- issue next stage's global loads (in flight during compute below)
        if (s < 31) {
            int s1   = s + 1;
            int esel = s1 >> 4;
            int kk   = s1 & 15;
            av = make_float4(0.f, 0.f, 0.f, 0.f);
            if (nrow >= 0) {
                av = aggrow[kk * 4 + cA];
                float g = esel ? gbr : gar;
                av.x *= g; av.y *= g; av.z *= g; av.w *= g;
            }
            const float4* W4n = (const float4*)(Ws + ((esel ? eb : ea) << 16) + (kk << 12));
            w0 = W4n[t]; w1 = W4n[t + 256]; w2 = W4n[t + 512]; w3 = W4n[t + 768];
        }
        // ---- compute current stage from LDS
        #pragma unroll
        for (int dd = 0; dd < 16; dd++) {
            float4 a = *(const float4*)&As[dd][r0];          // rows r0..r0+3 at k=dd
            const float* af = (const float*)&a;
            #pragma unroll
            for (int q = 0; q < 4; q++) {
                float4 w = *(const float4*)&WB[dd][q * 64 + c4];
                const float* wf = (const float*)&w;
                #pragma unroll
                for (int i = 0; i < 4; i++)
                    #pragma unroll
                    for (int k = 0; k < 4; k++)
                        acc[i][q * 4 + k] += af[i] * wf[k];
            }
        }
    }

    // epilogue
    #pragma unroll
    for (int i = 0; i < 4; i++) {
        int row = r0 + i;
        int n = nds[row];
        if (n < 0) continue;
        float ga = gA[row], gb = gB[row];
        #pragma unroll
        for (int q = 0; q < 4; q++) {
            int col = q * 64 + c4;
            float4 o;
            float* of = (float*)&o;
            #pragma unroll
            for (int k = 0; k < 4; k++) {
                float v = acc[i][q * 4 + k] + ga * shc[0][col + k] + gb * shc[1][col + k];
                of[k] = v + fmaxf(v, 0.f);
            }
            *(float4*)(hout + (size_t)n * DIM + col) = o;
        }
    }
}

// ================================================================ host
extern "C" void kernel_launch(void* const* d_in, const int* in_sizes, int n_in,
                              void* d_out, int out_size, void* d_ws, size_t ws_size,
                              hipStream_t stream) {
    const int*   x        = (const int*)d_in[0];
    const int*   ei       = (const int*)d_in[1];
    const float* emb      = (const float*)d_in[2];
    const float* w_gate   = (const float*)d_in[3];
    const float* conv_W   = (const float*)d_in[4];
    // conv_b (d_in[5]) cancels exactly in the BN fold — unused
    const float* bn_gamma = (const float*)d_in[6];
    const float* bn_beta  = (const float*)d_in[7];
    float* out = (float*)d_out;

    const int* src = ei;
    const int* dst = ei + NEDGE;

    char* ws = (char*)d_ws;
    size_t off = 0;
    auto alloc = [&](size_t bytes) -> void* {
        void* p = ws + off;
        off += (bytes + 255) & ~(size_t)255;
        return p;
    };
    float* h        = (float*)alloc((size_t)N_NODES * DIM * 4);   // single h buffer (in-place layers)
    float* agg      = (float*)alloc((size_t)N_NODES * DIM * 4);
    int*   cnt_out  = (int*)  alloc((size_t)N_NODES * 4);
    int*   cnt_in   = (int*)  alloc((size_t)N_NODES * 4);
    float* nsrc     = (float*)alloc((size_t)N_NODES * 4);
    float* ndst     = (float*)alloc((size_t)N_NODES * 4);
    int*   offs     = (int*)  alloc((size_t)(N_NODES + 1) * 4);
    int*   cursor   = (int*)  alloc((size_t)N_NODES * 4);
    int*   csr_s    = (int*)  alloc((size_t)NEDGE * 4);
    float* csr_w    = (float*)alloc((size_t)NEDGE * 4);
    int*   pid      = (int*)  alloc((size_t)N_NODES * 4);
    float* gaN      = (float*)alloc((size_t)N_NODES * 4);
    float* gbN      = (float*)alloc((size_t)N_NODES * 4);
    int*   gcount   = (int*)  alloc(6 * 4);
    int*   bnode    = (int*)  alloc((size_t)6 * N_NODES * 4);
    float* bga      = (float*)alloc((size_t)6 * N_NODES * 4);
    float* bgb      = (float*)alloc((size_t)6 * N_NODES * 4);
    float* Cp       = (float*)alloc((size_t)GSL * NPAIR * 4096 * 4); // 10.5 MB gram partials
    float* Cm       = (float*)alloc((size_t)DIM * DIM * 4);
    float* msum     = (float*)alloc((size_t)DIM * 4);
    float* scaleb   = (float*)alloc((size_t)NEXP * DIM * 4);
    float* shiftb   = (float*)alloc((size_t)NEXP * DIM * 4);
    float* Wsbuf    = (float*)alloc((size_t)NEXP * DIM * DIM * 4);
    (void)ws_size; (void)in_sizes; (void)n_in; (void)out_size;

    // ---- graph structure (per call; inputs are restored every call)
    hipMemsetAsync(cnt_out, 0, (size_t)N_NODES * 4, stream);
    hipMemsetAsync(cnt_in,  0, (size_t)N_NODES * 4, stream);
    k_deg <<<(NEDGE + 255) / 256, 256, 0, stream>>>(src, dst, cnt_out, cnt_in);
    k_norm<<<(N_NODES + 255) / 256, 256, 0, stream>>>(cnt_out, cnt_in, nsrc, ndst);
    k_scan<<<1, 1024, 0, stream>>>(cnt_in, offs, cursor);
    k_fill<<<(NEDGE + 255) / 256, 256, 0, stream>>>(src, dst, nsrc, cursor, csr_s, csr_w);
    k_emb <<<(N_NODES * 64 + 255) / 256, 256, 0, stream>>>(x, (const float4*)emb, (float4*)h);

    for (int l = 0; l < NLAYER; l++) {
        float* hout = (l == NLAYER - 1) ? out : h;   // k_moe reads only agg+buckets: in-place OK

        k_gate<<<N_NODES / 4, 256, 0, stream>>>((const float4*)h,
                (const float4*)(w_gate + (size_t)l * DIM * NEXP), pid, gaN, gbN);
        hipMemsetAsync(gcount, 0, 6 * 4, stream);
        k_bucket<<<(N_NODES + 255) / 256, 256, 0, stream>>>(pid, gaN, gbN,
                gcount, bnode, bga, bgb);
        k_agg<<<N_NODES / 4, 256, 0, stream>>>((const float4*)h, offs, csr_s, csr_w,
                ndst, (float4*)agg);

        hipMemsetAsync(msum, 0, (size_t)DIM * 4, stream);
        k_colsum<<<250, 256, 0, stream>>>(agg, msum);
        k_gram<<<dim3(GSL, NPAIR), 256, 0, stream>>>(agg, Cp);
        k_gred<<<DIM * DIM / 256, 256, 0, stream>>>(Cp, Cm);
        k_stats<<<NEXP * DIM, 256, 0, stream>>>(Cm, msum, conv_W, bn_gamma, bn_beta,
                                                scaleb, shiftb, l);
        k_wscale<<<(NEXP * DIM * DIM + 255) / 256, 256, 0, stream>>>(conv_W, scaleb, Wsbuf, l);

        k_moe<<<dim3((N_NODES + 63) / 64, 6), 256, 0, stream>>>((const float4*)agg,
                Wsbuf, shiftb, gcount, bnode, bga, bgb, hout);
    }
}

// Round 8
// 2048.805 us; speedup vs baseline: 5.2186x; 1.0976x over previous
//
#include <hip/hip_runtime.h>
#include <hip/hip_bf16.h>

#define N_NODES 50000
#define DIM     256
#define NEXP    4
#define NLAYER  3
#define NEDGE   1600000
#define BN_EPS  1e-5f

typedef __attribute__((ext_vector_type(8))) short          s16x8;
typedef __attribute__((ext_vector_type(8))) unsigned short u16x8;
typedef __attribute__((ext_vector_type(4))) float          f32x4;

// ---------------------------------------------------------------- utilities
static __device__ __forceinline__ float wave_reduce(float v) {
    #pragma unroll
    for (int off = 32; off; off >>= 1) v += __shfl_xor(v, off, 64);
    return v;
}

// split f32 into bf16 hi + bf16 lo (RNE); x ≈ hi + lo with |resid| <= 2^-18 |x|
static __device__ __forceinline__ void bf16split(float x, unsigned short& hi,
                                                 unsigned short& lo) {
    unsigned xb = __float_as_uint(x);
    unsigned hb = (xb + 0x7FFFu + ((xb >> 16) & 1u)) & 0xFFFF0000u;
    float hif = __uint_as_float(hb);
    float l  = x - hif;                       // exact (Sterbenz)
    unsigned lb2 = __float_as_uint(l);
    unsigned lb  = (lb2 + 0x7FFFu + ((lb2 >> 16) & 1u)) >> 16;
    hi = (unsigned short)(hb >> 16);
    lo = (unsigned short)lb;
}

// ---------------------------------------------------------------- degrees
__global__ void k_deg(const int* __restrict__ src, const int* __restrict__ dst,
                      int* __restrict__ cnt_out, int* __restrict__ cnt_in) {
    int i = blockIdx.x * 256 + threadIdx.x;
    if (i < NEDGE) {
        atomicAdd(&cnt_out[src[i]], 1);
        atomicAdd(&cnt_in[dst[i]], 1);
    }
}

__global__ void k_norm(const int* __restrict__ cnt_out, const int* __restrict__ cnt_in,
                       float* __restrict__ nsrc, float* __restrict__ ndst) {
    int i = blockIdx.x * 256 + threadIdx.x;
    if (i < N_NODES) {
        nsrc[i] = rsqrtf(fmaxf((float)cnt_out[i], 1.f));
        ndst[i] = rsqrtf(fmaxf((float)cnt_in[i], 1.f));
    }
}

// exclusive scan of cnt_in -> offs (N+1), also copy to cursor
__global__ __launch_bounds__(1024) void k_scan(const int* __restrict__ cnt_in,
                                               int* __restrict__ offs,
                                               int* __restrict__ cursor) {
    __shared__ int ps[1024];
    const int CH = 49;                       // 1024*49 = 50176 >= 50000
    int t = threadIdx.x;
    int base = t * CH;
    int s = 0;
    for (int k = 0; k < CH; k++) { int i = base + k; if (i < N_NODES) s += cnt_in[i]; }
    ps[t] = s; __syncthreads();
    for (int off = 1; off < 1024; off <<= 1) {
        int v = ps[t];
        int u = (t >= off) ? ps[t - off] : 0;
        __syncthreads();
        ps[t] = v + u;
        __syncthreads();
    }
    int run = (t == 0) ? 0 : ps[t - 1];
    for (int k = 0; k < CH; k++) {
        int i = base + k;
        if (i < N_NODES) { offs[i] = run; cursor[i] = run; run += cnt_in[i]; }
    }
    if (t == 1023) offs[N_NODES] = ps[1023];
}

__global__ void k_fill(const int* __restrict__ src, const int* __restrict__ dst,
                       int* __restrict__ cursor, int* __restrict__ csr_s) {
    int i = blockIdx.x * 256 + threadIdx.x;
    if (i < NEDGE) {
        int s = src[i], d = dst[i];
        int pos = atomicAdd(&cursor[d], 1);   // order varies per run -> k_agg must be
        csr_s[pos] = s;                       // order-invariant (fixed-point acc)
    }
}

// ---------------------------------------------------------------- embedding
__global__ void k_emb(const int* __restrict__ x, const float4* __restrict__ emb4,
                      float4* __restrict__ h4) {
    int i = blockIdx.x * 256 + threadIdx.x;   // N*64 float4s
    if (i < N_NODES * 64) {
        int n = i >> 6, c = i & 63;
        h4[i] = emb4[x[n] * 64 + c];
    }
}

// ---------------------------------------------------------------- gating: pid + (ga,gb) per node
// pair ids: (0,1)=0 (0,2)=1 (0,3)=2 (1,2)=3 (1,3)=4 (2,3)=5; ga = gate of lower-index expert
__global__ void k_gate(const float4* __restrict__ h4, const float4* __restrict__ wg4,
                       int* __restrict__ pid, float* __restrict__ gaN,
                       float* __restrict__ gbN) {
    int n    = blockIdx.x * 4 + (threadIdx.x >> 6);
    int lane = threadIdx.x & 63;
    if (n >= N_NODES) return;
    float4 hv = h4[n * 64 + lane];
    const float* hp = (const float*)&hv;
    float4 acc = {0.f, 0.f, 0.f, 0.f};
    #pragma unroll
    for (int j = 0; j < 4; j++) {
        float4 w = wg4[lane * 4 + j];   // w_gate[l][d][0..3]
        acc.x += hp[j] * w.x; acc.y += hp[j] * w.y;
        acc.z += hp[j] * w.z; acc.w += hp[j] * w.w;
    }
    acc.x = wave_reduce(acc.x); acc.y = wave_reduce(acc.y);
    acc.z = wave_reduce(acc.z); acc.w = wave_reduce(acc.w);
    if (lane == 0) {
        float lg[4] = {acc.x, acc.y, acc.z, acc.w};
        int e1 = 0;
        #pragma unroll
        for (int e = 1; e < 4; e++) if (lg[e] > lg[e1]) e1 = e;   // ties -> lower idx (top_k)
        int e2 = -1;
        #pragma unroll
        for (int e = 0; e < 4; e++) {
            if (e == e1) continue;
            if (e2 < 0 || lg[e] > lg[e2]) e2 = e;
        }
        float v1 = lg[e1], v2 = lg[e2];
        float g2 = 1.f / (1.f + expf(v1 - v2));   // softmax over {v1,v2}
        float g1 = 1.f - g2;
        int a = min(e1, e2), b = max(e1, e2);
        float ga = (e1 < e2) ? g1 : g2;
        float gb = (e1 < e2) ? g2 : g1;
        int p = (a == 0) ? (b - 1) : ((a == 1) ? (b + 1) : (b + 2));
        pid[n] = p; gaN[n] = ga; gbN[n] = gb;
    }
}

// ---------------------------------------------------------------- bucket nodes by pair id
// (order within bucket varies per run; k_moe output is per-node independent of tile mates)
__global__ void k_bucket(const int* __restrict__ pid,
                         int* __restrict__ gcount, int* __restrict__ bnode) {
    __shared__ int cnt[6];
    __shared__ int basep[6];
    int t = threadIdx.x;
    int n = blockIdx.x * 256 + t;
    if (t < 6) cnt[t] = 0;
    __syncthreads();
    int p = 0, pos = 0;
    bool valid = (n < N_NODES);
    if (valid) { p = pid[n]; pos = atomicAdd(&cnt[p], 1); }
    __syncthreads();
    if (t < 6) basep[t] = atomicAdd(&gcount[t], cnt[t]);
    __syncthreads();
    if (valid) bnode[p * N_NODES + basep[p] + pos] = n;
}

// ---------------------------------------------------------------- aggregation (one wave / dst)
// DETERMINISM: csr segment order varies run-to-run (atomic fill). Accumulate in
// fixed-point int64 (quantum 2^-32): integer addition is order-invariant -> h is
// bit-identical across runs regardless of atomic scheduling. Added error ~deg*2^-32.
__global__ void k_agg(const float4* __restrict__ h4,
                      const int* __restrict__ offs,
                      const int* __restrict__ csr_s, const float* __restrict__ nsrc,
                      const float* __restrict__ ndst,
                      float4* __restrict__ agg4) {
    const float S  = 4294967296.0f;        // 2^32 (exact exponent shift on w)
    const float SI = 1.0f / 4294967296.0f;
    int n    = blockIdx.x * 4 + (threadIdx.x >> 6);
    int lane = threadIdx.x & 63;
    if (n >= N_NODES) return;
    int beg = offs[n], end = offs[n + 1];
    long long ax = 0, ay = 0, az = 0, aw = 0;
    int j = beg;
    for (; j + 1 < end; j += 2) {          // unroll-2: two independent gathers in flight
        int   s0 = csr_s[j],     s1 = csr_s[j + 1];
        float w0 = nsrc[s0] * S, w1 = nsrc[s1] * S;
        float4 a = h4[(size_t)s0 * 64 + lane];
        float4 b = h4[(size_t)s1 * 64 + lane];
        ax += (long long)(w0 * a.x) + (long long)(w1 * b.x);
        ay += (long long)(w0 * a.y) + (long long)(w1 * b.y);
        az += (long long)(w0 * a.z) + (long long)(w1 * b.z);
        aw += (long long)(w0 * a.w) + (long long)(w1 * b.w);
    }
    if (j < end) {
        int   s0 = csr_s[j];
        float w0 = nsrc[s0] * S;
        float4 a = h4[(size_t)s0 * 64 + lane];
        ax += (long long)(w0 * a.x); ay += (long long)(w0 * a.y);
        az += (long long)(w0 * a.z); aw += (long long)(w0 * a.w);
    }
    float nd = ndst[n] * SI;
    float4 o;
    o.x = nd * (float)ax; o.y = nd * (float)ay;
    o.z = nd * (float)az; o.w = nd * (float)aw;
    agg4[n * 64 + lane] = o;
}

// ---------------------------------------------------------------- agg -> bf16 hi|lo pack [n][512]
__global__ void k_apack(const float* __restrict__ agg, unsigned short* __restrict__ Apk) {
    int i = blockIdx.x * 256 + threadIdx.x;
    if (i < N_NODES * DIM) {
        int n = i >> 8, k = i & 255;
        unsigned short hi, lo;
        bf16split(agg[i], hi, lo);
        Apk[(size_t)n * 512 + k]       = hi;
        Apk[(size_t)n * 512 + 256 + k] = lo;
    }
}

// ---------------------------------------------------------------- column sums of agg
// DETERMINISM: non-atomic partials + fixed-order reduce (msum feeds BN -> next-layer h).
__global__ void k_colsum(const float* __restrict__ agg, float* __restrict__ msum_p) {
    int t = threadIdx.x;                       // 256 threads == 256 columns
    const int CH = 200;                        // 250*200 = 50000
    int n0 = blockIdx.x * CH;
    float s = 0.f;
    for (int r = 0; r < CH; r++) {
        int n = n0 + r;
        if (n < N_NODES) s += agg[n * DIM + t];
    }
    msum_p[blockIdx.x * 256 + t] = s;
}

__global__ void k_msumred(const float* __restrict__ msum_p, float* __restrict__ msum) {
    int t = threadIdx.x;
    float s = 0.f;
    for (int b = 0; b < 250; b++) s += msum_p[b * 256 + t];
    msum[t] = s;
}

// ---------------------------------------------------------------- Gram partials (symmetric: 10 pairs)
#define GSL   48     // k-slices
#define GCH   1056   // rows per slice: 48*1056 = 50688 >= 50000 (multiple of 16)
#define NPAIR 10
__global__ __launch_bounds__(256) void k_gram(const float* __restrict__ agg,
                                              float* __restrict__ Cp) {
    __shared__ float LA[16][64];
    __shared__ float LB[16][64];
    const int tiT[NPAIR] = {0,0,0,0,1,1,1,2,2,3};
    const int tjT[NPAIR] = {0,1,2,3,1,2,3,2,3,3};
    int t  = threadIdx.x;
    int sl = blockIdx.x;            // k-slice
    int pr = blockIdx.y;            // tile pair 0..9 (ti<=tj)
    int ti = tiT[pr], tj = tjT[pr];
    int tx = t & 15, ty = t >> 4;
    float acc[4][4] = {};
    int nbase = sl * GCH;
    const float4* agg4 = (const float4*)agg;
    for (int s0 = 0; s0 < GCH; s0 += 16) {
        int r = ty;                  // 16 rows staged, one per thread group
        int n = nbase + s0 + r;
        float4 va = {0.f, 0.f, 0.f, 0.f}, vb = {0.f, 0.f, 0.f, 0.f};
        if (n < N_NODES) {
            va = agg4[n * 64 + ti * 16 + tx];
            vb = agg4[n * 64 + tj * 16 + tx];
        }
        __syncthreads();
        *(float4*)&LA[r][tx * 4] = va;
        *(float4*)&LB[r][tx * 4] = vb;
        __syncthreads();
        #pragma unroll
        for (int rr = 0; rr < 16; rr++) {
            float4 a = *(const float4*)&LA[rr][tx * 4];
            float4 b = *(const float4*)&LB[rr][ty * 4];
            const float* af = (const float*)&a;
            const float* bf = (const float*)&b;
            #pragma unroll
            for (int i = 0; i < 4; i++)
                #pragma unroll
                for (int j = 0; j < 4; j++)
                    acc[i][j] += af[i] * bf[j];
        }
    }
    float* Cb = Cp + ((size_t)(sl * NPAIR + pr)) * 4096;
    #pragma unroll
    for (int i = 0; i < 4; i++) {
        float4 v; v.x = acc[i][0]; v.y = acc[i][1]; v.z = acc[i][2]; v.w = acc[i][3];
        *(float4*)&Cb[(tx * 4 + i) * 64 + ty * 4] = v;
    }
}

__global__ void k_gred(const float* __restrict__ Cp, float* __restrict__ Cm) {
    int gid = blockIdx.x * 256 + threadIdx.x;    // 65536
    int i = gid >> 8, j = gid & 255;
    int a = i >> 6, b = j >> 6, ii = i & 63, jj = j & 63;
    int ro = ii, co = jj;
    if (a > b) { int tmp = a; a = b; b = tmp; ro = jj; co = ii; }   // symmetric reconstruct
    int pr = (a == 0) ? b : ((a == 1) ? 3 + b : ((a == 2) ? 5 + b : 6 + b));
    const float* p = Cp + (size_t)pr * 4096 + ro * 64 + co;
    float s = 0.f;
    #pragma unroll 8
    for (int sl = 0; sl < GSL; sl++) s += p[(size_t)sl * NPAIR * 4096];
    Cm[gid] = s;
}

// ---------------------------------------------------------------- BN stats -> scale/shift
__global__ __launch_bounds__(256) void k_stats(const float* __restrict__ C,
                                               const float* __restrict__ msum,
                                               const float* __restrict__ conv_W,
                                               const float* __restrict__ bn_gamma,
                                               const float* __restrict__ bn_beta,
                                               float* __restrict__ scaleb,
                                               float* __restrict__ shiftb, int l) {
    int e = blockIdx.x >> 8, f = blockIdx.x & 255;
    int t = threadIdx.x;
    __shared__ float wsh[256];
    __shared__ float red[256];
    const float* W = conv_W + (size_t)(l * NEXP + e) * DIM * DIM;  // [d][f]
    wsh[t] = W[t * DIM + f];
    __syncthreads();
    float v = 0.f;
    #pragma unroll 8
    for (int d2 = 0; d2 < DIM; d2++) v += C[d2 * DIM + t] * wsh[d2];  // C symmetric: column read
    float a_t = msum[t] * (1.f / (float)N_NODES);
    float qp  = wsh[t] * v;
    float ap  = a_t * wsh[t];
    red[t] = qp; __syncthreads();
    for (int off = 128; off; off >>= 1) { if (t < off) red[t] += red[t + off]; __syncthreads(); }
    float q = red[0];                       // only t==0 uses it
    red[t] = ap; __syncthreads();
    for (int off = 128; off; off >>= 1) { if (t < off) red[t] += red[t + off]; __syncthreads(); }
    if (t == 0) {
        float aw  = red[0];
        float var = q * (1.f / (float)N_NODES) - aw * aw;
        var = fmaxf(var, 0.f);
        float sg = bn_gamma[(l * NEXP + e) * DIM + f] * rsqrtf(var + BN_EPS);
        scaleb[e * DIM + f] = sg;
        shiftb[e * DIM + f] = bn_beta[(l * NEXP + e) * DIM + f] - aw * sg;
    }
}

// BN-folded W -> bf16 hi|lo, pre-transposed: Wpk[e][f][512] = [hi(k=0..255) | lo(k)]
__global__ void k_wscale(const float* __restrict__ conv_W, const float* __restrict__ scaleb,
                         unsigned short* __restrict__ Wpk, int l) {
    int i = blockIdx.x * 256 + threadIdx.x;     // e*65536 + f*256 + k  (k fastest)
    if (i < NEXP * DIM * DIM) {
        int k = i & 255, f = (i >> 8) & 255, e = i >> 16;
        float w = conv_W[(size_t)(l * NEXP + e) * 65536 + (size_t)k * 256 + f]
                * scaleb[e * 256 + f];
        unsigned short hi, lo;
        bf16split(w, hi, lo);
        size_t base = (size_t)(e * 256 + f) * 512;
        Wpk[base + k]       = hi;
        Wpk[base + 256 + k] = lo;
    }
}

// ---------------------------------------------------------------- pair-bucketed MoE GEMM via MFMA
// Split-bf16 x4 terms x2 experts = 64 K-steps of mfma_f32_16x16x32_bf16.
// out = ga*z_a + gb*z_b + ga*shA + gb*shB; ratio trick: acc = (ga/gb)*z_a + z_b, x gb at end.
// Gates applied in epilogue only (folding into bf16 A would destroy the hi/lo split).
// A-frag: A[m=lane&15][k=quad*8+j]; B-frag: B[k=quad*8+j][n=lane&15]; D: col=lane&15,row=quad*4+reg.
__global__ __launch_bounds__(256) void k_moe(const unsigned short* __restrict__ Apk,
                                             const unsigned short* __restrict__ Wpk,
                                             const float* __restrict__ shiftb,
                                             const int* __restrict__ gcount,
                                             const int* __restrict__ bnode,
                                             const float* __restrict__ gaN,
                                             const float* __restrict__ gbN,
                                             float* __restrict__ hout) {
    __shared__ short As2[64][40];     // pad 40: 2-way banking (free)
    __shared__ short Wt[256][40];     // transposed W tile [f][k]
    __shared__ int   nds[64];
    __shared__ float gA[64], gB[64];
    __shared__ float shc[2][256];
    int p    = blockIdx.y;
    int cnt  = gcount[p];
    int base = blockIdx.x * 64;
    if (base >= cnt) return;
    const int eaT[6] = {0,0,0,1,1,2};
    const int ebT[6] = {1,2,3,2,3,3};
    int ea = eaT[p], eb = ebT[p];
    int t  = threadIdx.x;
    if (t < 64) {
        int idx = base + t;
        if (idx < cnt) {
            int n = bnode[p * N_NODES + idx];
            nds[t] = n; gA[t] = gaN[n]; gB[t] = gbN[n];
        } else { nds[t] = -1; gA[t] = 0.f; gB[t] = 0.f; }
    }
    if (t < 128) {   // stage both shift rows
        int which = t >> 6, c = t & 63;
        int e = which ? eb : ea;
        ((float4*)shc[which])[c] = ((const float4*)(shiftb + e * DIM))[c];
    }
    __syncthreads();

    // staging roles (no lambdas! round-4 lesson)
    int rA   = t >> 2;            // A row 0..63
    int cA8  = (t & 3) * 8;       // 8 ushorts within 32-k chunk
    int fsub = t >> 2;            // W f-row sub-index
    int wc8  = (t & 3) * 8;

    int nrow = nds[rA];
    const unsigned short* arow = Apk + (size_t)(nrow < 0 ? 0 : nrow) * 512;

    // prefetch stage 0: expert ea, term hh, kc=0 -> aoff=0, woff=0
    u16x8 areg = {0,0,0,0,0,0,0,0};
    if (nrow >= 0) areg = *(const u16x8*)(arow + cA8);
    u16x8 wreg0, wreg1, wreg2, wreg3;
    {
        const unsigned short* wb = Wpk + (size_t)(ea * 256) * 512 + wc8;
        wreg0 = *(const u16x8*)(wb + (size_t)(fsub)       * 512);
        wreg1 = *(const u16x8*)(wb + (size_t)(64  + fsub) * 512);
        wreg2 = *(const u16x8*)(wb + (size_t)(128 + fsub) * 512);
        wreg3 = *(const u16x8*)(wb + (size_t)(192 + fsub) * 512);
    }

    int wv = t >> 6, lane = t & 63, quad = lane >> 4, l16 = lane & 15;
    f32x4 acc[4][4];
    #pragma unroll
    for (int a = 0; a < 4; a++)
        #pragma unroll
        for (int b = 0; b < 4; b++) { f32x4 z = {0.f,0.f,0.f,0.f}; acc[a][b] = z; }

    for (int s = 0; s < 64; s++) {
        __syncthreads();               // previous compute done reading LDS
        *(u16x8*)&As2[rA][cA8] = areg;
        *(u16x8*)&Wt[fsub][wc8]       = wreg0;
        *(u16x8*)&Wt[64  + fsub][wc8] = wreg1;
        *(u16x8*)&Wt[128 + fsub][wc8] = wreg2;
        *(u16x8*)&Wt[192 + fsub][wc8] = wreg3;
        __syncthreads();
        if (s < 63) {                  // prefetch next stage (in flight during MFMA)
            int s1   = s + 1;
            int esel = s1 >> 5;                    // 0: ea, 1: eb
            int t2   = (s1 >> 3) & 3;              // term: hh, hl, lh, ll
            int kc   = (s1 & 7) * 32;
            int aoff = (t2 >= 2 ? 256 : 0) + kc;   // Ahi for t2 0,1; Alo for 2,3
            int woff = ((t2 & 1) ? 256 : 0) + kc;  // Whi for even t2, Wlo for odd
            u16x8 z8 = {0,0,0,0,0,0,0,0};
            areg = z8;
            if (nrow >= 0) areg = *(const u16x8*)(arow + aoff + cA8);
            const unsigned short* wb = Wpk + (size_t)((esel ? eb : ea) * 256) * 512
                                     + woff + wc8;
            wreg0 = *(const u16x8*)(wb + (size_t)(fsub)       * 512);
            wreg1 = *(const u16x8*)(wb + (size_t)(64  + fsub) * 512);
            wreg2 = *(const u16x8*)(wb + (size_t)(128 + fsub) * 512);
            wreg3 = *(const u16x8*)(wb + (size_t)(192 + fsub) * 512);
        }
        // compute: 16 MFMA on this 32-k chunk
        s16x8 af[4], bfr[4];
        #pragma unroll
        for (int rt = 0; rt < 4; rt++)
            af[rt] = *(const s16x8*)&As2[rt * 16 + l16][quad * 8];
        #pragma unroll
        for (int ct = 0; ct < 4; ct++)
            bfr[ct] = *(const s16x8*)&Wt[wv * 64 + ct * 16 + l16][quad * 8];
        #pragma unroll
        for (int rt = 0; rt < 4; rt++)
            #pragma unroll
            for (int ct = 0; ct < 4; ct++)
                acc[rt][ct] = __builtin_amdgcn_mfma_f32_16x16x32_bf16(
                                  af[rt], bfr[ct], acc[rt][ct], 0, 0, 0);
        if (s == 31) {   // expert-a done: acc *= ga/gb per row
            #pragma unroll
            for (int rt = 0; rt < 4; rt++)
                #pragma unroll
                for (int r = 0; r < 4; r++) {
                    int row = rt * 16 + quad * 4 + r;
                    float ratio = gA[row] / fmaxf(gB[row], 1e-30f);
                    #pragma unroll
                    for (int ct = 0; ct < 4; ct++) acc[rt][ct][r] *= ratio;
                }
        }
    }

    // epilogue: out = gb*acc + ga*shA + gb*shB; h = v + relu(v)
    #pragma unroll
    for (int rt = 0; rt < 4; rt++)
        #pragma unroll
        for (int r = 0; r < 4; r++) {
            int row = rt * 16 + quad * 4 + r;
            int n = nds[row];
            if (n < 0) continue;
            float gaL = gA[row];
            float gbL = fmaxf(gB[row], 1e-30f);
            #pragma unroll
            for (int ct = 0; ct < 4; ct++) {
                int col = wv * 64 + ct * 16 + l16;
                float v = gbL * acc[rt][ct][r] + gaL * shc[0][col] + gbL * shc[1][col];
                hout[(size_t)n * DIM + col] = v + fmaxf(v, 0.f);
            }
        }
}

// ================================================================ host
extern "C" void kernel_launch(void* const* d_in, const int* in_sizes, int n_in,
                              void* d_out, int out_size, void* d_ws, size_t ws_size,
                              hipStream_t stream) {
    const int*   x        = (const int*)d_in[0];
    const int*   ei       = (const int*)d_in[1];
    const float* emb      = (const float*)d_in[2];
    const float* w_gate   = (const float*)d_in[3];
    const float* conv_W   = (const float*)d_in[4];
    // conv_b (d_in[5]) cancels exactly in the BN fold — unused
    const float* bn_gamma = (const float*)d_in[6];
    const float* bn_beta  = (const float*)d_in[7];
    float* out = (float*)d_out;

    const int* src = ei;
    const int* dst = ei + NEDGE;

    char* ws = (char*)d_ws;
    size_t off = 0;
    auto alloc = [&](size_t bytes) -> void* {
        void* p = ws + off;
        off += (bytes + 255) & ~(size_t)255;
        return p;
    };
    float*          h       = (float*)alloc((size_t)N_NODES * DIM * 4);
    float*          agg     = (float*)alloc((size_t)N_NODES * DIM * 4);
    unsigned short* Apk     = (unsigned short*)alloc((size_t)N_NODES * 512 * 2);
    int*            cnt_out = (int*)  alloc((size_t)N_NODES * 4);
    int*            cnt_in  = (int*)  alloc((size_t)N_NODES * 4);
    float*          nsrc    = (float*)alloc((size_t)N_NODES * 4);
    float*          ndst    = (float*)alloc((size_t)N_NODES * 4);
    int*            offs    = (int*)  alloc((size_t)(N_NODES + 1) * 4);
    int*            cursor  = (int*)  alloc((size_t)N_NODES * 4);
    int*            csr_s   = (int*)  alloc((size_t)NEDGE * 4);
    int*            pid     = (int*)  alloc((size_t)N_NODES * 4);
    float*          gaN     = (float*)alloc((size_t)N_NODES * 4);
    float*          gbN     = (float*)alloc((size_t)N_NODES * 4);
    int*            gcount  = (int*)  alloc(6 * 4);
    int*            bnode   = (int*)  alloc((size_t)6 * N_NODES * 4);
    float*          Cp      = (float*)alloc((size_t)GSL * NPAIR * 4096 * 4);
    float*          Cm      = (float*)alloc((size_t)DIM * DIM * 4);
    float*          msum_p  = (float*)alloc((size_t)250 * 256 * 4);
    float*          msum    = (float*)alloc((size_t)DIM * 4);
    float*          scaleb  = (float*)alloc((size_t)NEXP * DIM * 4);
    float*          shiftb  = (float*)alloc((size_t)NEXP * DIM * 4);
    unsigned short* Wpk     = (unsigned short*)alloc((size_t)NEXP * DIM * 512 * 2);
    (void)ws_size; (void)in_sizes; (void)n_in; (void)out_size;

    // ---- graph structure (per call; inputs are restored every call)
    hipMemsetAsync(cnt_out, 0, (size_t)N_NODES * 4, stream);
    hipMemsetAsync(cnt_in,  0, (size_t)N_NODES * 4, stream);
    k_deg <<<(NEDGE + 255) / 256, 256, 0, stream>>>(src, dst, cnt_out, cnt_in);
    k_norm<<<(N_NODES + 255) / 256, 256, 0, stream>>>(cnt_out, cnt_in, nsrc, ndst);
    k_scan<<<1, 1024, 0, stream>>>(cnt_in, offs, cursor);
    k_fill<<<(NEDGE + 255) / 256, 256, 0, stream>>>(src, dst, cursor, csr_s);
    k_emb <<<(N_NODES * 64 + 255) / 256, 256, 0, stream>>>(x, (const float4*)emb, (float4*)h);

    for (int l = 0; l < NLAYER; l++) {
        float* hout = (l == NLAYER - 1) ? out : h;   // k_moe reads only Apk+buckets: in-place OK

        k_gate<<<N_NODES / 4, 256, 0, stream>>>((const float4*)h,
                (const float4*)(w_gate + (size_t)l * DIM * NEXP), pid, gaN, gbN);
        hipMemsetAsync(gcount, 0, 6 * 4, stream);
        k_bucket<<<(N_NODES + 255) / 256, 256, 0, stream>>>(pid, gcount, bnode);
        k_agg<<<N_NODES / 4, 256, 0, stream>>>((const float4*)h, offs, csr_s, nsrc,
                ndst, (float4*)agg);
        k_apack<<<(N_NODES * DIM + 255) / 256, 256, 0, stream>>>(agg, Apk);

        k_colsum<<<250, 256, 0, stream>>>(agg, msum_p);
        k_msumred<<<1, 256, 0, stream>>>(msum_p, msum);
        k_gram<<<dim3(GSL, NPAIR), 256, 0, stream>>>(agg, Cp);
        k_gred<<<DIM * DIM / 256, 256, 0, stream>>>(Cp, Cm);
        k_stats<<<NEXP * DIM, 256, 0, stream>>>(Cm, msum, conv_W, bn_gamma, bn_beta,
                                                scaleb, shiftb, l);
        k_wscale<<<(NEXP * DIM * DIM + 255) / 256, 256, 0, stream>>>(conv_W, scaleb, Wpk, l);

        k_moe<<<dim3((N_NODES + 63) / 64, 6), 256, 0, stream>>>(Apk, Wpk, shiftb,
                gcount, bnode, gaN, gbN, hout);
    }
}